// Round 1
// baseline (429.422 us; speedup 1.0000x reference)
//
#include <hip/hip_runtime.h>

#define F_DIMC 64
#define K_DIMC 16
#define NGRAPH 64

// ---------------- workspace layout (bytes) ----------------
// [0,256)        hist (int[64])
// [256,512)      cursor (int[64])
// [512,768)      den (float[64])
// [768,1024)     pad
// [1024,66560)   dense_raw (float[64*256])
// [66560,132096) ssbuf (float[64*256])
// [132096,541696) deg (float[N])            <- all above zeroed each call
// [541696,541952) offsets (int[64])
// [541952,7095552) sel (float[N*16])
// [7095552,7505152) q (float[N])
// [7505152,14058752) sorted (uint2[E])

__global__ void k_selection(const float* __restrict__ node_attr,
                            const float* __restrict__ W,
                            const float* __restrict__ bias,
                            float* __restrict__ sel,
                            float* __restrict__ q,
                            int N) {
    __shared__ float sW[K_DIMC][F_DIMC];
    __shared__ float sb[K_DIMC];
    int t = threadIdx.x;
    for (int idx = t; idx < F_DIMC * K_DIMC; idx += blockDim.x) {
        int f = idx / K_DIMC, k = idx % K_DIMC;
        sW[k][f] = W[idx];
    }
    if (t < K_DIMC) sb[t] = bias[t];
    __syncthreads();
    int n = blockIdx.x * blockDim.x + t;
    if (n >= N) return;

    const float4* xr = (const float4*)(node_attr + (size_t)n * F_DIMC);
    float4 x[F_DIMC / 4];
#pragma unroll
    for (int f4 = 0; f4 < F_DIMC / 4; ++f4) x[f4] = xr[f4];

    float logits[K_DIMC];
#pragma unroll
    for (int k = 0; k < K_DIMC; ++k) {
        const float4* wk = (const float4*)&sW[k][0];
        float acc = sb[k];
#pragma unroll
        for (int f4 = 0; f4 < F_DIMC / 4; ++f4) {
            float4 w = wk[f4];
            acc += x[f4].x * w.x + x[f4].y * w.y + x[f4].z * w.z + x[f4].w * w.w;
        }
        logits[k] = acc;
    }
    float m = logits[0];
#pragma unroll
    for (int k = 1; k < K_DIMC; ++k) m = fmaxf(m, logits[k]);
    float sum = 0.f;
#pragma unroll
    for (int k = 0; k < K_DIMC; ++k) {
        float e = __expf(logits[k] - m);
        logits[k] = e;
        sum += e;
    }
    float inv = 1.f / sum;
    float qq = 0.f;
    float4* sd = (float4*)(sel + (size_t)n * K_DIMC);
#pragma unroll
    for (int k4 = 0; k4 < K_DIMC / 4; ++k4) {
        float4 v;
        v.x = logits[4 * k4 + 0] * inv;
        v.y = logits[4 * k4 + 1] * inv;
        v.z = logits[4 * k4 + 2] * inv;
        v.w = logits[4 * k4 + 3] * inv;
        qq += v.x * v.x + v.y * v.y + v.z * v.z + v.w * v.w;
        sd[k4] = v;
    }
    q[n] = qq;
}

__global__ void k_hist(const int* __restrict__ row, const int* __restrict__ batchv,
                       int* __restrict__ hist, float* __restrict__ deg, int E) {
    __shared__ int lh[NGRAPH];
    if (threadIdx.x < NGRAPH) lh[threadIdx.x] = 0;
    __syncthreads();
    int e = blockIdx.x * blockDim.x + threadIdx.x;
    if (e < E) {
        int r = row[e];
        int g = batchv[r];
        atomicAdd(&lh[g], 1);
        atomicAdd(&deg[r], 1.0f);
    }
    __syncthreads();
    if (threadIdx.x < NGRAPH) {
        int c = lh[threadIdx.x];
        if (c) atomicAdd(&hist[threadIdx.x], c);
    }
}

__global__ void k_scan(const int* __restrict__ hist, int* __restrict__ offsets,
                       int* __restrict__ cursor) {
    int t = threadIdx.x;  // 64 threads = 1 wave
    int v = hist[t];
    int sum = v;
#pragma unroll
    for (int d = 1; d < 64; d <<= 1) {
        int o = __shfl_up(sum, d);
        if (t >= d) sum += o;
    }
    int excl = sum - v;
    offsets[t] = excl;
    cursor[t] = excl;
}

__global__ void k_scatter(const int* __restrict__ row, const int* __restrict__ col,
                          const int* __restrict__ batchv, int* __restrict__ cursor,
                          uint2* __restrict__ sorted, int E) {
    __shared__ int lcnt[NGRAPH];
    __shared__ int lbase[NGRAPH];
    if (threadIdx.x < NGRAPH) lcnt[threadIdx.x] = 0;
    __syncthreads();
    int e = blockIdx.x * blockDim.x + threadIdx.x;
    int r = 0, c = 0, g = 0, lpos = 0;
    bool valid = e < E;
    if (valid) {
        r = row[e];
        c = col[e];
        g = batchv[r];
        lpos = atomicAdd(&lcnt[g], 1);
    }
    __syncthreads();
    if (threadIdx.x < NGRAPH) {
        int cnt = lcnt[threadIdx.x];
        lbase[threadIdx.x] = cnt ? atomicAdd(&cursor[threadIdx.x], cnt) : 0;
    }
    __syncthreads();
    if (valid) {
        sorted[(size_t)lbase[g] + lpos] = make_uint2((unsigned)r, (unsigned)c);
    }
}

// one wave owns all 256 cells of the 16x16 accumulator: lane l -> (i=l>>2, j=(l&3)*4..+3)
__global__ void k_adj(const uint2* __restrict__ sorted, const int* __restrict__ offsets,
                      const int* __restrict__ hist, const float* __restrict__ sel,
                      float* __restrict__ dense_raw) {
    int g = blockIdx.y;
    int start = offsets[g];
    int cnt = hist[g];
    int wavesPerGraph = gridDim.x * (blockDim.x >> 6);
    int wseq = blockIdx.x * (blockDim.x >> 6) + (threadIdx.x >> 6);
    int lane = threadIdx.x & 63;
    int i = lane >> 2;
    int j0 = (lane & 3) * 4;
    float ax = 0.f, ay = 0.f, az = 0.f, aw = 0.f;
#pragma unroll 4
    for (int e = wseq; e < cnt; e += wavesPerGraph) {
        uint2 pr = sorted[(size_t)start + e];
        float a = sel[(size_t)pr.x * K_DIMC + i];
        float4 bv = *(const float4*)(sel + (size_t)pr.y * K_DIMC + j0);
        ax += a * bv.x;
        ay += a * bv.y;
        az += a * bv.z;
        aw += a * bv.w;
    }
    float* dst = dense_raw + (g * K_DIMC * K_DIMC + i * K_DIMC + j0);
    atomicAdd(dst + 0, ax);
    atomicAdd(dst + 1, ay);
    atomicAdd(dst + 2, az);
    atomicAdd(dst + 3, aw);
}

__global__ void k_den(const float* __restrict__ deg, const float* __restrict__ q,
                      float* __restrict__ den, int perG) {
    int g = blockIdx.x;
    float s = 0.f;
    for (int n = threadIdx.x; n < perG; n += blockDim.x) {
        size_t idx = (size_t)g * perG + n;
        s += deg[idx] * q[idx];
    }
    int lane = threadIdx.x & 63;
    int wid = threadIdx.x >> 6;
#pragma unroll
    for (int off = 32; off > 0; off >>= 1) s += __shfl_down(s, off);
    __shared__ float red[8];
    if (lane == 0) red[wid] = s;
    __syncthreads();
    if (threadIdx.x == 0) {
        float tot = 0.f;
        int nw = blockDim.x >> 6;
        for (int w = 0; w < nw; ++w) tot += red[w];
        den[g] = tot;
    }
}

// lane l -> k=l>>2, sub=l&3 ; owns SX cells [k][sub*16..+15] and SS cells [k][sub*4..+3]
__global__ void k_sx(const float* __restrict__ sel, const float* __restrict__ x,
                     float* __restrict__ ssbuf, float* __restrict__ out, int perG) {
    int g = blockIdx.y;
    int wavesPerGraph = gridDim.x * (blockDim.x >> 6);
    int wseq = blockIdx.x * (blockDim.x >> 6) + (threadIdx.x >> 6);
    int lane = threadIdx.x & 63;
    int k = lane >> 2;
    int sub = lane & 3;
    int f0 = sub * 16;
    int j0 = sub * 4;
    float accss[4] = {0.f, 0.f, 0.f, 0.f};
    float accsx[16];
#pragma unroll
    for (int j = 0; j < 16; ++j) accsx[j] = 0.f;
    size_t base = (size_t)g * perG;
#pragma unroll 2
    for (int nn = wseq; nn < perG; nn += wavesPerGraph) {
        size_t node = base + nn;
        float a = sel[node * K_DIMC + k];
        float4 s4 = *(const float4*)(sel + node * K_DIMC + j0);
        accss[0] += a * s4.x;
        accss[1] += a * s4.y;
        accss[2] += a * s4.z;
        accss[3] += a * s4.w;
        const float4* xv = (const float4*)(x + node * F_DIMC + f0);
#pragma unroll
        for (int j = 0; j < 4; ++j) {
            float4 v = xv[j];
            accsx[4 * j + 0] += a * v.x;
            accsx[4 * j + 1] += a * v.y;
            accsx[4 * j + 2] += a * v.z;
            accsx[4 * j + 3] += a * v.w;
        }
    }
    float* ssd = ssbuf + (g * 256 + k * K_DIMC + j0);
    atomicAdd(ssd + 0, accss[0]);
    atomicAdd(ssd + 1, accss[1]);
    atomicAdd(ssd + 2, accss[2]);
    atomicAdd(ssd + 3, accss[3]);
    float* sxd = out + ((size_t)(g * K_DIMC + k)) * F_DIMC + f0;
#pragma unroll
    for (int j = 0; j < 16; ++j) atomicAdd(sxd + j, accsx[j]);
}

__global__ void k_fin(const float* __restrict__ dense_raw, const float* __restrict__ ssbuf,
                      const float* __restrict__ den, float* __restrict__ out) {
    int g = threadIdx.x;  // 64 threads, one per graph
    const float* A = dense_raw + g * 256;
    float dv[K_DIMC];
#pragma unroll
    for (int k = 0; k < K_DIMC; ++k) {
        float s = 0.f;
#pragma unroll
        for (int j = 0; j < K_DIMC; ++j) s += A[k * K_DIMC + j];
        dv[k] = sqrtf(s) + 1e-15f;
    }
    float* Ao = out + NGRAPH * K_DIMC * F_DIMC + g * 256;
    float tr = 0.f;
#pragma unroll
    for (int k = 0; k < K_DIMC; ++k) {
#pragma unroll
        for (int j = 0; j < K_DIMC; ++j) {
            float v = A[k * K_DIMC + j] / (dv[k] * dv[j]);
            Ao[k * K_DIMC + j] = v;
            if (k == j) tr += v;
        }
    }
    float mterm = -(tr / den[g]);

    const float* SS = ssbuf + g * 256;
    float nrm2 = 0.f;
    for (int c = 0; c < 256; ++c) nrm2 += SS[c] * SS[c];
    float invn = 1.f / sqrtf(nrm2);
    float osum = 0.f;
#pragma unroll
    for (int k = 0; k < K_DIMC; ++k) {
#pragma unroll
        for (int j = 0; j < K_DIMC; ++j) {
            float v = SS[k * K_DIMC + j] * invn - ((k == j) ? 0.25f : 0.f);
            osum += v * v;
        }
    }
    float og = sqrtf(osum);

    float a = mterm, b2 = og;
#pragma unroll
    for (int off = 32; off > 0; off >>= 1) {
        a += __shfl_down(a, off);
        b2 += __shfl_down(b2, off);
    }
    if (g == 0) {
        out[NGRAPH * K_DIMC * F_DIMC + NGRAPH * K_DIMC * K_DIMC + 0] = a / (float)NGRAPH;
        out[NGRAPH * K_DIMC * F_DIMC + NGRAPH * K_DIMC * K_DIMC + 1] = b2 / (float)NGRAPH;
    }
}

extern "C" void kernel_launch(void* const* d_in, const int* in_sizes, int n_in,
                              void* d_out, int out_size, void* d_ws, size_t ws_size,
                              hipStream_t stream) {
    const float* node_attr = (const float*)d_in[0];
    const float* W = (const float*)d_in[1];
    const float* bias = (const float*)d_in[2];
    const int* edge_index = (const int*)d_in[3];
    const int* batchv = (const int*)d_in[4];
    // d_in[5] = num_graphs (device scalar); geometry fixed: B=64
    int N = in_sizes[0] / F_DIMC;
    int E = in_sizes[3] / 2;
    const int* row = edge_index;
    const int* col = edge_index + E;
    float* out = (float*)d_out;
    char* ws = (char*)d_ws;

    int* hist = (int*)(ws + 0);
    int* cursor = (int*)(ws + 256);
    float* den = (float*)(ws + 512);
    float* dense_raw = (float*)(ws + 1024);
    float* ssbuf = (float*)(ws + 66560);
    float* deg = (float*)(ws + 132096);
    int* offsets = (int*)(ws + 541696);
    float* sel = (float*)(ws + 541952);
    float* q = (float*)(ws + 7095552);
    uint2* sorted = (uint2*)(ws + 7505152);

    // zero accumulators (hist/cursor/den/dense_raw/ss/deg) and the SX output region
    hipMemsetAsync(ws, 0, 541696, stream);
    hipMemsetAsync(out, 0, (size_t)NGRAPH * K_DIMC * F_DIMC * sizeof(float), stream);

    k_selection<<<(N + 255) / 256, 256, 0, stream>>>(node_attr, W, bias, sel, q, N);
    k_hist<<<(E + 511) / 512, 512, 0, stream>>>(row, batchv, hist, deg, E);
    k_scan<<<1, 64, 0, stream>>>(hist, offsets, cursor);
    k_scatter<<<(E + 511) / 512, 512, 0, stream>>>(row, col, batchv, cursor, sorted, E);
    k_adj<<<dim3(32, NGRAPH), 256, 0, stream>>>(sorted, offsets, hist, sel, dense_raw);
    k_den<<<NGRAPH, 256, 0, stream>>>(deg, q, den, N / NGRAPH);
    k_sx<<<dim3(8, NGRAPH), 256, 0, stream>>>(sel, node_attr, ssbuf, out, N / NGRAPH);
    k_fin<<<1, 64, 0, stream>>>(dense_raw, ssbuf, den, out);
}

// Round 2
// 336.390 us; speedup vs baseline: 1.2766x; 1.2766x over previous
//
#include <hip/hip_runtime.h>

#define F_DIMC 64
#define K_DIMC 16
#define NGRAPH 64
#define SX_WAVES 8

// ---------------- workspace layout (bytes) ----------------
// zeroed each call: [0, 476160)
//   [0,256)        hist (int[64])
//   [256,512)      cursor (int[64])
//   [512,768)      den (float[64])
//   [768,1024)     pad
//   [1024,66560)   dense_raw (float[64*256])
//   [66560,476160) deg (float[N])
// not zeroed:
//   [476160,476416)   offsets (int[64])
//   [476416,541952)   ssbuf (float[64*256])   (stored, not accumulated)
//   [541952,7095552)  sel (float[N*16])
//   [7095552,7505152) q (float[N])
//   [7505152,14058752) sorted (uint2[E])

__global__ void k_selection(const float* __restrict__ node_attr,
                            const float* __restrict__ W,
                            const float* __restrict__ bias,
                            float* __restrict__ sel,
                            float* __restrict__ q,
                            int N) {
    __shared__ float sW[K_DIMC][F_DIMC];
    __shared__ float sb[K_DIMC];
    int t = threadIdx.x;
    for (int idx = t; idx < F_DIMC * K_DIMC; idx += blockDim.x) {
        int f = idx / K_DIMC, k = idx % K_DIMC;
        sW[k][f] = W[idx];
    }
    if (t < K_DIMC) sb[t] = bias[t];
    __syncthreads();
    int n = blockIdx.x * blockDim.x + t;
    if (n >= N) return;

    const float4* xr = (const float4*)(node_attr + (size_t)n * F_DIMC);
    float4 x[F_DIMC / 4];
#pragma unroll
    for (int f4 = 0; f4 < F_DIMC / 4; ++f4) x[f4] = xr[f4];

    float logits[K_DIMC];
#pragma unroll
    for (int k = 0; k < K_DIMC; ++k) {
        const float4* wk = (const float4*)&sW[k][0];
        float acc = sb[k];
#pragma unroll
        for (int f4 = 0; f4 < F_DIMC / 4; ++f4) {
            float4 w = wk[f4];
            acc += x[f4].x * w.x + x[f4].y * w.y + x[f4].z * w.z + x[f4].w * w.w;
        }
        logits[k] = acc;
    }
    float m = logits[0];
#pragma unroll
    for (int k = 1; k < K_DIMC; ++k) m = fmaxf(m, logits[k]);
    float sum = 0.f;
#pragma unroll
    for (int k = 0; k < K_DIMC; ++k) {
        float e = __expf(logits[k] - m);
        logits[k] = e;
        sum += e;
    }
    float inv = 1.f / sum;
    float qq = 0.f;
    float4* sd = (float4*)(sel + (size_t)n * K_DIMC);
#pragma unroll
    for (int k4 = 0; k4 < K_DIMC / 4; ++k4) {
        float4 v;
        v.x = logits[4 * k4 + 0] * inv;
        v.y = logits[4 * k4 + 1] * inv;
        v.z = logits[4 * k4 + 2] * inv;
        v.w = logits[4 * k4 + 3] * inv;
        qq += v.x * v.x + v.y * v.y + v.z * v.z + v.w * v.w;
        sd[k4] = v;
    }
    q[n] = qq;
}

__global__ void k_hist(const int* __restrict__ row, const int* __restrict__ batchv,
                       int* __restrict__ hist, float* __restrict__ deg, int E) {
    __shared__ int lh[NGRAPH];
    if (threadIdx.x < NGRAPH) lh[threadIdx.x] = 0;
    __syncthreads();
    int e = blockIdx.x * blockDim.x + threadIdx.x;
    if (e < E) {
        int r = row[e];
        int g = batchv[r];
        atomicAdd(&lh[g], 1);
        atomicAdd(&deg[r], 1.0f);
    }
    __syncthreads();
    if (threadIdx.x < NGRAPH) {
        int c = lh[threadIdx.x];
        if (c) atomicAdd(&hist[threadIdx.x], c);
    }
}

__global__ void k_scan(const int* __restrict__ hist, int* __restrict__ offsets,
                       int* __restrict__ cursor) {
    int t = threadIdx.x;  // 64 threads = 1 wave
    int v = hist[t];
    int sum = v;
#pragma unroll
    for (int d = 1; d < 64; d <<= 1) {
        int o = __shfl_up(sum, d);
        if (t >= d) sum += o;
    }
    int excl = sum - v;
    offsets[t] = excl;
    cursor[t] = excl;
}

__global__ void k_scatter(const int* __restrict__ row, const int* __restrict__ col,
                          const int* __restrict__ batchv, int* __restrict__ cursor,
                          uint2* __restrict__ sorted, int E) {
    __shared__ int lcnt[NGRAPH];
    __shared__ int lbase[NGRAPH];
    if (threadIdx.x < NGRAPH) lcnt[threadIdx.x] = 0;
    __syncthreads();
    int e = blockIdx.x * blockDim.x + threadIdx.x;
    int r = 0, c = 0, g = 0, lpos = 0;
    bool valid = e < E;
    if (valid) {
        r = row[e];
        c = col[e];
        g = batchv[r];
        lpos = atomicAdd(&lcnt[g], 1);
    }
    __syncthreads();
    if (threadIdx.x < NGRAPH) {
        int cnt = lcnt[threadIdx.x];
        lbase[threadIdx.x] = cnt ? atomicAdd(&cursor[threadIdx.x], cnt) : 0;
    }
    __syncthreads();
    if (valid) {
        sorted[(size_t)lbase[g] + lpos] = make_uint2((unsigned)r, (unsigned)c);
    }
}

// lane l -> (i=l>>2, j=(l&3)*4..+3); per-block LDS reduce across 4 waves,
// then ONE atomicAdd per cell per block (16 blocks/graph -> 262K atomics total).
__global__ __launch_bounds__(256) void k_adj(const uint2* __restrict__ sorted,
                                             const int* __restrict__ offsets,
                                             const int* __restrict__ hist,
                                             const float* __restrict__ sel,
                                             float* __restrict__ dense_raw) {
    int g = blockIdx.y;
    int start = offsets[g];
    int cnt = hist[g];
    int wavesPerGraph = gridDim.x * 4;
    int wid = threadIdx.x >> 6;
    int wseq = blockIdx.x * 4 + wid;
    int lane = threadIdx.x & 63;
    int i = lane >> 2;
    int j0 = (lane & 3) * 4;
    float ax = 0.f, ay = 0.f, az = 0.f, aw = 0.f;
#pragma unroll 4
    for (int e = wseq; e < cnt; e += wavesPerGraph) {
        uint2 pr = sorted[(size_t)start + e];
        float a = sel[(size_t)pr.x * K_DIMC + i];
        float4 bv = *(const float4*)(sel + (size_t)pr.y * K_DIMC + j0);
        ax += a * bv.x;
        ay += a * bv.y;
        az += a * bv.z;
        aw += a * bv.w;
    }
    __shared__ float lacc[4][256];
    int cell = i * K_DIMC + j0;
    float4* lw = (float4*)&lacc[wid][cell];
    *lw = make_float4(ax, ay, az, aw);
    __syncthreads();
    int c = threadIdx.x;  // 256 threads, one cell each
    float s = lacc[0][c] + lacc[1][c] + lacc[2][c] + lacc[3][c];
    atomicAdd(dense_raw + g * 256 + c, s);
}

// one block per graph, 8 waves; lane l -> k=l>>2, sub=l&3;
// owns SX cells [k][sub*16..+15], SS cells [k][sub*4..+3]; LDS reduce, direct store.
__global__ __launch_bounds__(512) void k_sx(const float* __restrict__ sel,
                                            const float* __restrict__ x,
                                            float* __restrict__ ssbuf,
                                            float* __restrict__ out, int perG) {
    int g = blockIdx.x;
    int wid = threadIdx.x >> 6;
    int lane = threadIdx.x & 63;
    int k = lane >> 2;
    int sub = lane & 3;
    int f0 = sub * 16;
    int j0 = sub * 4;
    float accss[4] = {0.f, 0.f, 0.f, 0.f};
    float accsx[16];
#pragma unroll
    for (int j = 0; j < 16; ++j) accsx[j] = 0.f;
    size_t base = (size_t)g * perG;
#pragma unroll 2
    for (int nn = wid; nn < perG; nn += SX_WAVES) {
        size_t node = base + nn;
        float a = sel[node * K_DIMC + k];
        float4 s4 = *(const float4*)(sel + node * K_DIMC + j0);
        accss[0] += a * s4.x;
        accss[1] += a * s4.y;
        accss[2] += a * s4.z;
        accss[3] += a * s4.w;
        const float4* xv = (const float4*)(x + node * F_DIMC + f0);
#pragma unroll
        for (int j = 0; j < 4; ++j) {
            float4 v = xv[j];
            accsx[4 * j + 0] += a * v.x;
            accsx[4 * j + 1] += a * v.y;
            accsx[4 * j + 2] += a * v.z;
            accsx[4 * j + 3] += a * v.w;
        }
    }
    __shared__ float lsx[SX_WAVES][K_DIMC * F_DIMC];  // 32 KB
    __shared__ float lss[SX_WAVES][256];              // 8 KB
#pragma unroll
    for (int j4 = 0; j4 < 4; ++j4) {
        float4* d = (float4*)&lsx[wid][k * F_DIMC + f0 + 4 * j4];
        *d = make_float4(accsx[4 * j4], accsx[4 * j4 + 1], accsx[4 * j4 + 2], accsx[4 * j4 + 3]);
    }
    {
        float4* d = (float4*)&lss[wid][k * K_DIMC + j0];
        *d = make_float4(accss[0], accss[1], accss[2], accss[3]);
    }
    __syncthreads();
    // SX: 1024 cells, 512 threads -> 2 cells each; cell c = k*64 + f, matches out layout
    for (int c = threadIdx.x; c < K_DIMC * F_DIMC; c += 512) {
        float s = 0.f;
#pragma unroll
        for (int w = 0; w < SX_WAVES; ++w) s += lsx[w][c];
        out[(size_t)g * (K_DIMC * F_DIMC) + c] = s;
    }
    if (threadIdx.x < 256) {
        int c = threadIdx.x;
        float s = 0.f;
#pragma unroll
        for (int w = 0; w < SX_WAVES; ++w) s += lss[w][c];
        ssbuf[g * 256 + c] = s;
    }
}

__global__ void k_den(const float* __restrict__ deg, const float* __restrict__ q,
                      float* __restrict__ den, int perG) {
    int g = blockIdx.x;
    float s = 0.f;
    for (int n = threadIdx.x; n < perG; n += blockDim.x) {
        size_t idx = (size_t)g * perG + n;
        s += deg[idx] * q[idx];
    }
    int lane = threadIdx.x & 63;
    int wid = threadIdx.x >> 6;
#pragma unroll
    for (int off = 32; off > 0; off >>= 1) s += __shfl_down(s, off);
    __shared__ float red[8];
    if (lane == 0) red[wid] = s;
    __syncthreads();
    if (threadIdx.x == 0) {
        float tot = 0.f;
        int nw = blockDim.x >> 6;
        for (int w = 0; w < nw; ++w) tot += red[w];
        den[g] = tot;
    }
}

__global__ void k_fin(const float* __restrict__ dense_raw, const float* __restrict__ ssbuf,
                      const float* __restrict__ den, float* __restrict__ out) {
    int g = threadIdx.x;  // 64 threads, one per graph
    const float* A = dense_raw + g * 256;
    float dv[K_DIMC];
#pragma unroll
    for (int k = 0; k < K_DIMC; ++k) {
        float s = 0.f;
#pragma unroll
        for (int j = 0; j < K_DIMC; ++j) s += A[k * K_DIMC + j];
        dv[k] = sqrtf(s) + 1e-15f;
    }
    float* Ao = out + NGRAPH * K_DIMC * F_DIMC + g * 256;
    float tr = 0.f;
#pragma unroll
    for (int k = 0; k < K_DIMC; ++k) {
#pragma unroll
        for (int j = 0; j < K_DIMC; ++j) {
            float v = A[k * K_DIMC + j] / (dv[k] * dv[j]);
            Ao[k * K_DIMC + j] = v;
            if (k == j) tr += v;
        }
    }
    float mterm = -(tr / den[g]);

    const float* SS = ssbuf + g * 256;
    float nrm2 = 0.f;
    for (int c = 0; c < 256; ++c) nrm2 += SS[c] * SS[c];
    float invn = 1.f / sqrtf(nrm2);
    float osum = 0.f;
#pragma unroll
    for (int k = 0; k < K_DIMC; ++k) {
#pragma unroll
        for (int j = 0; j < K_DIMC; ++j) {
            float v = SS[k * K_DIMC + j] * invn - ((k == j) ? 0.25f : 0.f);
            osum += v * v;
        }
    }
    float og = sqrtf(osum);

    float a = mterm, b2 = og;
#pragma unroll
    for (int off = 32; off > 0; off >>= 1) {
        a += __shfl_down(a, off);
        b2 += __shfl_down(b2, off);
    }
    if (g == 0) {
        out[NGRAPH * K_DIMC * F_DIMC + NGRAPH * K_DIMC * K_DIMC + 0] = a / (float)NGRAPH;
        out[NGRAPH * K_DIMC * F_DIMC + NGRAPH * K_DIMC * K_DIMC + 1] = b2 / (float)NGRAPH;
    }
}

extern "C" void kernel_launch(void* const* d_in, const int* in_sizes, int n_in,
                              void* d_out, int out_size, void* d_ws, size_t ws_size,
                              hipStream_t stream) {
    const float* node_attr = (const float*)d_in[0];
    const float* W = (const float*)d_in[1];
    const float* bias = (const float*)d_in[2];
    const int* edge_index = (const int*)d_in[3];
    const int* batchv = (const int*)d_in[4];
    int N = in_sizes[0] / F_DIMC;
    int E = in_sizes[3] / 2;
    const int* row = edge_index;
    const int* col = edge_index + E;
    float* out = (float*)d_out;
    char* ws = (char*)d_ws;

    int* hist = (int*)(ws + 0);
    int* cursor = (int*)(ws + 256);
    float* den = (float*)(ws + 512);
    float* dense_raw = (float*)(ws + 1024);
    float* deg = (float*)(ws + 66560);
    int* offsets = (int*)(ws + 476160);
    float* ssbuf = (float*)(ws + 476416);
    float* sel = (float*)(ws + 541952);
    float* q = (float*)(ws + 7095552);
    uint2* sorted = (uint2*)(ws + 7505152);

    // zero hist/cursor/den/dense_raw/deg in one contiguous memset
    hipMemsetAsync(ws, 0, 476160, stream);

    k_selection<<<(N + 255) / 256, 256, 0, stream>>>(node_attr, W, bias, sel, q, N);
    k_hist<<<(E + 511) / 512, 512, 0, stream>>>(row, batchv, hist, deg, E);
    k_scan<<<1, 64, 0, stream>>>(hist, offsets, cursor);
    k_scatter<<<(E + 511) / 512, 512, 0, stream>>>(row, col, batchv, cursor, sorted, E);
    k_adj<<<dim3(16, NGRAPH), 256, 0, stream>>>(sorted, offsets, hist, sel, dense_raw);
    k_den<<<NGRAPH, 256, 0, stream>>>(deg, q, den, N / NGRAPH);
    k_sx<<<NGRAPH, 512, 0, stream>>>(sel, node_attr, ssbuf, out, N / NGRAPH);
    k_fin<<<1, 64, 0, stream>>>(dense_raw, ssbuf, den, out);
}

// Round 3
// 269.188 us; speedup vs baseline: 1.5953x; 1.2496x over previous
//
#include <hip/hip_runtime.h>

#define F_DIMC 64
#define K_DIMC 16
#define NGRAPH 64
#define SX_WAVES 8
#define SX_SPLIT 8
#define ADJ_SPLIT 32

// ---------------- workspace layout (bytes) ----------------
// zeroed each call: [0, 541696)
//   [0,256)         hist (int[64])
//   [256,512)       cursor (int[64])
//   [512,768)       den (float[64])
//   [768,1024)      pad
//   [1024,66560)    dense_raw (float[64*256])
//   [66560,132096)  ssbuf (float[64*256])
//   [132096,541696) deg (float[N])
// not zeroed:
//   [541696,541952)   offsets (int[64])
//   [541952,7095552)  sel (float[N*16])
//   [7095552,7505152) q (float[N])
//   [7505152,14058752) sorted (uint2[E])

__global__ void k_selection(const float* __restrict__ node_attr,
                            const float* __restrict__ W,
                            const float* __restrict__ bias,
                            float* __restrict__ sel,
                            float* __restrict__ q,
                            int N) {
    __shared__ float sW[K_DIMC][F_DIMC];
    __shared__ float sb[K_DIMC];
    int t = threadIdx.x;
    for (int idx = t; idx < F_DIMC * K_DIMC; idx += blockDim.x) {
        int f = idx / K_DIMC, k = idx % K_DIMC;
        sW[k][f] = W[idx];
    }
    if (t < K_DIMC) sb[t] = bias[t];
    __syncthreads();
    int n = blockIdx.x * blockDim.x + t;
    if (n >= N) return;

    const float4* xr = (const float4*)(node_attr + (size_t)n * F_DIMC);
    float4 x[F_DIMC / 4];
#pragma unroll
    for (int f4 = 0; f4 < F_DIMC / 4; ++f4) x[f4] = xr[f4];

    float logits[K_DIMC];
#pragma unroll
    for (int k = 0; k < K_DIMC; ++k) {
        const float4* wk = (const float4*)&sW[k][0];
        float acc = sb[k];
#pragma unroll
        for (int f4 = 0; f4 < F_DIMC / 4; ++f4) {
            float4 w = wk[f4];
            acc += x[f4].x * w.x + x[f4].y * w.y + x[f4].z * w.z + x[f4].w * w.w;
        }
        logits[k] = acc;
    }
    float m = logits[0];
#pragma unroll
    for (int k = 1; k < K_DIMC; ++k) m = fmaxf(m, logits[k]);
    float sum = 0.f;
#pragma unroll
    for (int k = 0; k < K_DIMC; ++k) {
        float e = __expf(logits[k] - m);
        logits[k] = e;
        sum += e;
    }
    float inv = 1.f / sum;
    float qq = 0.f;
    float4* sd = (float4*)(sel + (size_t)n * K_DIMC);
#pragma unroll
    for (int k4 = 0; k4 < K_DIMC / 4; ++k4) {
        float4 v;
        v.x = logits[4 * k4 + 0] * inv;
        v.y = logits[4 * k4 + 1] * inv;
        v.z = logits[4 * k4 + 2] * inv;
        v.w = logits[4 * k4 + 3] * inv;
        qq += v.x * v.x + v.y * v.y + v.z * v.z + v.w * v.w;
        sd[k4] = v;
    }
    q[n] = qq;
}

__global__ void k_hist(const int* __restrict__ row, int* __restrict__ hist,
                       float* __restrict__ deg, int E, int perG) {
    __shared__ int lh[NGRAPH];
    if (threadIdx.x < NGRAPH) lh[threadIdx.x] = 0;
    __syncthreads();
    int e = blockIdx.x * blockDim.x + threadIdx.x;
    if (e < E) {
        int r = row[e];
        int g = r / perG;
        atomicAdd(&lh[g], 1);
        atomicAdd(&deg[r], 1.0f);
    }
    __syncthreads();
    if (threadIdx.x < NGRAPH) {
        int c = lh[threadIdx.x];
        if (c) atomicAdd(&hist[threadIdx.x], c);
    }
}

__global__ void k_scan(const int* __restrict__ hist, int* __restrict__ offsets,
                       int* __restrict__ cursor) {
    int t = threadIdx.x;  // 64 threads = 1 wave
    int v = hist[t];
    int sum = v;
#pragma unroll
    for (int d = 1; d < 64; d <<= 1) {
        int o = __shfl_up(sum, d);
        if (t >= d) sum += o;
    }
    int excl = sum - v;
    offsets[t] = excl;
    cursor[t] = excl;
}

__global__ void k_scatter(const int* __restrict__ row, const int* __restrict__ col,
                          int* __restrict__ cursor, uint2* __restrict__ sorted,
                          int E, int perG) {
    __shared__ int lcnt[NGRAPH];
    __shared__ int lbase[NGRAPH];
    if (threadIdx.x < NGRAPH) lcnt[threadIdx.x] = 0;
    __syncthreads();
    int e = blockIdx.x * blockDim.x + threadIdx.x;
    int r = 0, c = 0, g = 0, lpos = 0;
    bool valid = e < E;
    if (valid) {
        r = row[e];
        c = col[e];
        g = r / perG;
        lpos = atomicAdd(&lcnt[g], 1);
    }
    __syncthreads();
    if (threadIdx.x < NGRAPH) {
        int cnt = lcnt[threadIdx.x];
        lbase[threadIdx.x] = cnt ? atomicAdd(&cursor[threadIdx.x], cnt) : 0;
    }
    __syncthreads();
    if (valid) {
        sorted[(size_t)lbase[g] + lpos] = make_uint2((unsigned)r, (unsigned)c);
    }
}

// wave processes one edge per iteration; lane l -> (i=l>>2, j=(l&3)*4..+3).
// per-block LDS reduce across 4 waves, then ONE atomicAdd per cell per block.
__global__ __launch_bounds__(256) void k_adj(const uint2* __restrict__ sorted,
                                             const int* __restrict__ offsets,
                                             const int* __restrict__ hist,
                                             const float* __restrict__ sel,
                                             float* __restrict__ dense_raw) {
    int g = blockIdx.y;
    int start = offsets[g];
    int cnt = hist[g];
    int wavesPerGraph = gridDim.x * 4;
    int wid = threadIdx.x >> 6;
    int wseq = blockIdx.x * 4 + wid;
    int lane = threadIdx.x & 63;
    int i = lane >> 2;
    int j0 = (lane & 3) * 4;
    float ax = 0.f, ay = 0.f, az = 0.f, aw = 0.f;
#pragma unroll 8
    for (int e = wseq; e < cnt; e += wavesPerGraph) {
        uint2 pr = sorted[(size_t)start + e];
        float a = sel[(size_t)pr.x * K_DIMC + i];
        float4 bv = *(const float4*)(sel + (size_t)pr.y * K_DIMC + j0);
        ax += a * bv.x;
        ay += a * bv.y;
        az += a * bv.z;
        aw += a * bv.w;
    }
    __shared__ float lacc[4][256];
    int cell = i * K_DIMC + j0;
    float4* lw = (float4*)&lacc[wid][cell];
    *lw = make_float4(ax, ay, az, aw);
    __syncthreads();
    int c = threadIdx.x;  // 256 threads, one cell each
    float s = lacc[0][c] + lacc[1][c] + lacc[2][c] + lacc[3][c];
    atomicAdd(dense_raw + g * 256 + c, s);
}

// grid (SX_SPLIT, NGRAPH), 8 waves/block; lane l -> k=l>>2, sub=l&3;
// owns SX cells [k][sub*16..+15], SS cells [k][sub*4..+3].
// LDS reduce within block, then one atomicAdd per cell per block (8 contenders).
// Also fuses mincut_den: lane 0 accumulates deg[n]*q[n] over its wave's nodes.
__global__ __launch_bounds__(512) void k_sx(const float* __restrict__ sel,
                                            const float* __restrict__ x,
                                            const float* __restrict__ deg,
                                            const float* __restrict__ q,
                                            float* __restrict__ ssbuf,
                                            float* __restrict__ den,
                                            float* __restrict__ out, int perG) {
    int g = blockIdx.y;
    int wid = threadIdx.x >> 6;
    int wslot = blockIdx.x * SX_WAVES + wid;     // 0..63
    int lane = threadIdx.x & 63;
    int k = lane >> 2;
    int sub = lane & 3;
    int f0 = sub * 16;
    int j0 = sub * 4;
    float accss[4] = {0.f, 0.f, 0.f, 0.f};
    float accsx[16];
#pragma unroll
    for (int j = 0; j < 16; ++j) accsx[j] = 0.f;
    float dacc = 0.f;
    size_t base = (size_t)g * perG;
    int stride = SX_SPLIT * SX_WAVES;            // 64
#pragma unroll 2
    for (int nn = wslot; nn < perG; nn += stride) {
        size_t node = base + nn;
        float a = sel[node * K_DIMC + k];
        float4 s4 = *(const float4*)(sel + node * K_DIMC + j0);
        accss[0] += a * s4.x;
        accss[1] += a * s4.y;
        accss[2] += a * s4.z;
        accss[3] += a * s4.w;
        if (lane == 0) dacc += deg[node] * q[node];
        const float4* xv = (const float4*)(x + node * F_DIMC + f0);
#pragma unroll
        for (int j = 0; j < 4; ++j) {
            float4 v = xv[j];
            accsx[4 * j + 0] += a * v.x;
            accsx[4 * j + 1] += a * v.y;
            accsx[4 * j + 2] += a * v.z;
            accsx[4 * j + 3] += a * v.w;
        }
    }
    __shared__ float lsx[SX_WAVES][K_DIMC * F_DIMC];  // 32 KB
    __shared__ float lss[SX_WAVES][256];              // 8 KB
    __shared__ float dred[SX_WAVES];
#pragma unroll
    for (int j4 = 0; j4 < 4; ++j4) {
        float4* d = (float4*)&lsx[wid][k * F_DIMC + f0 + 4 * j4];
        *d = make_float4(accsx[4 * j4], accsx[4 * j4 + 1], accsx[4 * j4 + 2], accsx[4 * j4 + 3]);
    }
    {
        float4* d = (float4*)&lss[wid][k * K_DIMC + j0];
        *d = make_float4(accss[0], accss[1], accss[2], accss[3]);
    }
    if (lane == 0) dred[wid] = dacc;
    __syncthreads();
    // SX: 1024 cells, 512 threads -> 2 cells each; cell c = k*64 + f matches out layout
    for (int c = threadIdx.x; c < K_DIMC * F_DIMC; c += 512) {
        float s = 0.f;
#pragma unroll
        for (int w = 0; w < SX_WAVES; ++w) s += lsx[w][c];
        atomicAdd(out + (size_t)g * (K_DIMC * F_DIMC) + c, s);
    }
    if (threadIdx.x < 256) {
        int c = threadIdx.x;
        float s = 0.f;
#pragma unroll
        for (int w = 0; w < SX_WAVES; ++w) s += lss[w][c];
        atomicAdd(ssbuf + g * 256 + c, s);
    }
    if (threadIdx.x == 256 + 0) {
        float s = 0.f;
#pragma unroll
        for (int w = 0; w < SX_WAVES; ++w) s += dred[w];
        atomicAdd(den + g, s);
    }
}

__global__ void k_fin(const float* __restrict__ dense_raw, const float* __restrict__ ssbuf,
                      const float* __restrict__ den, float* __restrict__ out) {
    int g = threadIdx.x;  // 64 threads, one per graph
    const float* A = dense_raw + g * 256;
    float dv[K_DIMC];
#pragma unroll
    for (int k = 0; k < K_DIMC; ++k) {
        float s = 0.f;
#pragma unroll
        for (int j = 0; j < K_DIMC; ++j) s += A[k * K_DIMC + j];
        dv[k] = sqrtf(s) + 1e-15f;
    }
    float* Ao = out + NGRAPH * K_DIMC * F_DIMC + g * 256;
    float tr = 0.f;
#pragma unroll
    for (int k = 0; k < K_DIMC; ++k) {
#pragma unroll
        for (int j = 0; j < K_DIMC; ++j) {
            float v = A[k * K_DIMC + j] / (dv[k] * dv[j]);
            Ao[k * K_DIMC + j] = v;
            if (k == j) tr += v;
        }
    }
    float mterm = -(tr / den[g]);

    const float* SS = ssbuf + g * 256;
    float nrm2 = 0.f;
    for (int c = 0; c < 256; ++c) nrm2 += SS[c] * SS[c];
    float invn = 1.f / sqrtf(nrm2);
    float osum = 0.f;
#pragma unroll
    for (int k = 0; k < K_DIMC; ++k) {
#pragma unroll
        for (int j = 0; j < K_DIMC; ++j) {
            float v = SS[k * K_DIMC + j] * invn - ((k == j) ? 0.25f : 0.f);
            osum += v * v;
        }
    }
    float og = sqrtf(osum);

    float a = mterm, b2 = og;
#pragma unroll
    for (int off = 32; off > 0; off >>= 1) {
        a += __shfl_down(a, off);
        b2 += __shfl_down(b2, off);
    }
    if (g == 0) {
        out[NGRAPH * K_DIMC * F_DIMC + NGRAPH * K_DIMC * K_DIMC + 0] = a / (float)NGRAPH;
        out[NGRAPH * K_DIMC * F_DIMC + NGRAPH * K_DIMC * K_DIMC + 1] = b2 / (float)NGRAPH;
    }
}

extern "C" void kernel_launch(void* const* d_in, const int* in_sizes, int n_in,
                              void* d_out, int out_size, void* d_ws, size_t ws_size,
                              hipStream_t stream) {
    const float* node_attr = (const float*)d_in[0];
    const float* W = (const float*)d_in[1];
    const float* bias = (const float*)d_in[2];
    const int* edge_index = (const int*)d_in[3];
    int N = in_sizes[0] / F_DIMC;
    int E = in_sizes[3] / 2;
    int perG = N / NGRAPH;
    const int* row = edge_index;
    const int* col = edge_index + E;
    float* out = (float*)d_out;
    char* ws = (char*)d_ws;

    int* hist = (int*)(ws + 0);
    int* cursor = (int*)(ws + 256);
    float* den = (float*)(ws + 512);
    float* dense_raw = (float*)(ws + 1024);
    float* ssbuf = (float*)(ws + 66560);
    float* deg = (float*)(ws + 132096);
    int* offsets = (int*)(ws + 541696);
    float* sel = (float*)(ws + 541952);
    float* q = (float*)(ws + 7095552);
    uint2* sorted = (uint2*)(ws + 7505152);

    // zero hist/cursor/den/dense_raw/ssbuf/deg in one contiguous memset,
    // plus the SX region of out (accumulated by atomics now)
    hipMemsetAsync(ws, 0, 541696, stream);
    hipMemsetAsync(out, 0, (size_t)NGRAPH * K_DIMC * F_DIMC * sizeof(float), stream);

    k_selection<<<(N + 255) / 256, 256, 0, stream>>>(node_attr, W, bias, sel, q, N);
    k_hist<<<(E + 511) / 512, 512, 0, stream>>>(row, hist, deg, E, perG);
    k_scan<<<1, 64, 0, stream>>>(hist, offsets, cursor);
    k_scatter<<<(E + 511) / 512, 512, 0, stream>>>(row, col, cursor, sorted, E, perG);
    k_adj<<<dim3(ADJ_SPLIT, NGRAPH), 256, 0, stream>>>(sorted, offsets, hist, sel, dense_raw);
    k_sx<<<dim3(SX_SPLIT, NGRAPH), 512, 0, stream>>>(sel, node_attr, deg, q, ssbuf, den, out, perG);
    k_fin<<<1, 64, 0, stream>>>(dense_raw, ssbuf, den, out);
}

// Round 4
// 210.777 us; speedup vs baseline: 2.0373x; 1.2771x over previous
//
#include <hip/hip_runtime.h>

#define F_DIMC 64
#define K_DIMC 16
#define NGRAPH 64
#define SX_WAVES 8
#define SX_SPLIT 8
#define ADJ_SPLIT 32

// ---------------- workspace layout (bytes) ----------------
// zeroed each call: [0, 132096)
//   [0,256)         hist (int[64])
//   [256,512)       cursor (int[64])
//   [512,768)       den (float[64])
//   [768,1024)      pad
//   [1024,66560)    dense_raw (float[64*256])
//   [66560,132096)  ssbuf (float[64*256])
// not zeroed:
//   [132096,132352)    offsets (int[64])
//   [132352,6685952)   sel (float[N*16])
//   [6685952,7095552)  q (float[N])
//   [7095552,13649152) sorted (uint2[E])

__global__ void k_selection(const float* __restrict__ node_attr,
                            const float* __restrict__ W,
                            const float* __restrict__ bias,
                            float* __restrict__ sel,
                            float* __restrict__ q,
                            int N) {
    __shared__ float sW[K_DIMC][F_DIMC];
    __shared__ float sb[K_DIMC];
    int t = threadIdx.x;
    for (int idx = t; idx < F_DIMC * K_DIMC; idx += blockDim.x) {
        int f = idx / K_DIMC, k = idx % K_DIMC;
        sW[k][f] = W[idx];
    }
    if (t < K_DIMC) sb[t] = bias[t];
    __syncthreads();
    int n = blockIdx.x * blockDim.x + t;
    if (n >= N) return;

    const float4* xr = (const float4*)(node_attr + (size_t)n * F_DIMC);
    float4 x[F_DIMC / 4];
#pragma unroll
    for (int f4 = 0; f4 < F_DIMC / 4; ++f4) x[f4] = xr[f4];

    float logits[K_DIMC];
#pragma unroll
    for (int k = 0; k < K_DIMC; ++k) {
        const float4* wk = (const float4*)&sW[k][0];
        float acc = sb[k];
#pragma unroll
        for (int f4 = 0; f4 < F_DIMC / 4; ++f4) {
            float4 w = wk[f4];
            acc += x[f4].x * w.x + x[f4].y * w.y + x[f4].z * w.z + x[f4].w * w.w;
        }
        logits[k] = acc;
    }
    float m = logits[0];
#pragma unroll
    for (int k = 1; k < K_DIMC; ++k) m = fmaxf(m, logits[k]);
    float sum = 0.f;
#pragma unroll
    for (int k = 0; k < K_DIMC; ++k) {
        float e = __expf(logits[k] - m);
        logits[k] = e;
        sum += e;
    }
    float inv = 1.f / sum;
    float qq = 0.f;
    float4* sd = (float4*)(sel + (size_t)n * K_DIMC);
#pragma unroll
    for (int k4 = 0; k4 < K_DIMC / 4; ++k4) {
        float4 v;
        v.x = logits[4 * k4 + 0] * inv;
        v.y = logits[4 * k4 + 1] * inv;
        v.z = logits[4 * k4 + 2] * inv;
        v.w = logits[4 * k4 + 3] * inv;
        qq += v.x * v.x + v.y * v.y + v.z * v.z + v.w * v.w;
        sd[k4] = v;
    }
    q[n] = qq;
}

// histogram of edges per graph + mincut_den[g] = sum_e q[row_e] (deg telescopes out).
// 4 edges per thread via int4 loads; LDS accumulation; 64+64 global atomics per block.
__global__ __launch_bounds__(512) void k_hist(const int* __restrict__ row,
                                              const float* __restrict__ q,
                                              int* __restrict__ hist,
                                              float* __restrict__ den,
                                              int E4, int perG) {
    __shared__ int lh[NGRAPH];
    __shared__ float lden[NGRAPH];
    if (threadIdx.x < NGRAPH) {
        lh[threadIdx.x] = 0;
        lden[threadIdx.x] = 0.f;
    }
    __syncthreads();
    int e4 = blockIdx.x * blockDim.x + threadIdx.x;
    if (e4 < E4) {
        int4 r4 = ((const int4*)row)[e4];
        int r[4] = {r4.x, r4.y, r4.z, r4.w};
#pragma unroll
        for (int j = 0; j < 4; ++j) {
            int g = r[j] / perG;
            atomicAdd(&lh[g], 1);
            atomicAdd(&lden[g], q[r[j]]);
        }
    }
    __syncthreads();
    if (threadIdx.x < NGRAPH) {
        int c = lh[threadIdx.x];
        if (c) {
            atomicAdd(&hist[threadIdx.x], c);
            atomicAdd(&den[threadIdx.x], lden[threadIdx.x]);
        }
    }
}

__global__ void k_scan(const int* __restrict__ hist, int* __restrict__ offsets,
                       int* __restrict__ cursor) {
    int t = threadIdx.x;  // 64 threads = 1 wave
    int v = hist[t];
    int sum = v;
#pragma unroll
    for (int d = 1; d < 64; d <<= 1) {
        int o = __shfl_up(sum, d);
        if (t >= d) sum += o;
    }
    int excl = sum - v;
    offsets[t] = excl;
    cursor[t] = excl;
}

__global__ void k_scatter(const int* __restrict__ row, const int* __restrict__ col,
                          int* __restrict__ cursor, uint2* __restrict__ sorted,
                          int E, int perG) {
    __shared__ int lcnt[NGRAPH];
    __shared__ int lbase[NGRAPH];
    if (threadIdx.x < NGRAPH) lcnt[threadIdx.x] = 0;
    __syncthreads();
    int e = blockIdx.x * blockDim.x + threadIdx.x;
    int r = 0, c = 0, g = 0, lpos = 0;
    bool valid = e < E;
    if (valid) {
        r = row[e];
        c = col[e];
        g = r / perG;
        lpos = atomicAdd(&lcnt[g], 1);
    }
    __syncthreads();
    if (threadIdx.x < NGRAPH) {
        int cnt = lcnt[threadIdx.x];
        lbase[threadIdx.x] = cnt ? atomicAdd(&cursor[threadIdx.x], cnt) : 0;
    }
    __syncthreads();
    if (valid) {
        sorted[(size_t)lbase[g] + lpos] = make_uint2((unsigned)r, (unsigned)c);
    }
}

// wave processes one edge per iteration; lane l -> (i=l>>2, j=(l&3)*4..+3).
// per-block LDS reduce across 4 waves, then ONE atomicAdd per cell per block.
__global__ __launch_bounds__(256) void k_adj(const uint2* __restrict__ sorted,
                                             const int* __restrict__ offsets,
                                             const int* __restrict__ hist,
                                             const float* __restrict__ sel,
                                             float* __restrict__ dense_raw) {
    int g = blockIdx.y;
    int start = offsets[g];
    int cnt = hist[g];
    int wavesPerGraph = gridDim.x * 4;
    int wid = threadIdx.x >> 6;
    int wseq = blockIdx.x * 4 + wid;
    int lane = threadIdx.x & 63;
    int i = lane >> 2;
    int j0 = (lane & 3) * 4;
    float ax = 0.f, ay = 0.f, az = 0.f, aw = 0.f;
#pragma unroll 8
    for (int e = wseq; e < cnt; e += wavesPerGraph) {
        uint2 pr = sorted[(size_t)start + e];
        float a = sel[(size_t)pr.x * K_DIMC + i];
        float4 bv = *(const float4*)(sel + (size_t)pr.y * K_DIMC + j0);
        ax += a * bv.x;
        ay += a * bv.y;
        az += a * bv.z;
        aw += a * bv.w;
    }
    __shared__ float lacc[4][256];
    int cell = i * K_DIMC + j0;
    float4* lw = (float4*)&lacc[wid][cell];
    *lw = make_float4(ax, ay, az, aw);
    __syncthreads();
    int c = threadIdx.x;  // 256 threads, one cell each
    float s = lacc[0][c] + lacc[1][c] + lacc[2][c] + lacc[3][c];
    atomicAdd(dense_raw + g * 256 + c, s);
}

// grid (SX_SPLIT, NGRAPH), 8 waves/block; lane l -> k=l>>2, sub=l&3;
// owns SX cells [k][sub*16..+15], SS cells [k][sub*4..+3].
// LDS reduce within block, then one atomicAdd per cell per block (8 contenders).
__global__ __launch_bounds__(512) void k_sx(const float* __restrict__ sel,
                                            const float* __restrict__ x,
                                            float* __restrict__ ssbuf,
                                            float* __restrict__ out, int perG) {
    int g = blockIdx.y;
    int wid = threadIdx.x >> 6;
    int wslot = blockIdx.x * SX_WAVES + wid;     // 0..63
    int lane = threadIdx.x & 63;
    int k = lane >> 2;
    int sub = lane & 3;
    int f0 = sub * 16;
    int j0 = sub * 4;
    float accss[4] = {0.f, 0.f, 0.f, 0.f};
    float accsx[16];
#pragma unroll
    for (int j = 0; j < 16; ++j) accsx[j] = 0.f;
    size_t base = (size_t)g * perG;
    int stride = SX_SPLIT * SX_WAVES;            // 64
#pragma unroll 2
    for (int nn = wslot; nn < perG; nn += stride) {
        size_t node = base + nn;
        float a = sel[node * K_DIMC + k];
        float4 s4 = *(const float4*)(sel + node * K_DIMC + j0);
        accss[0] += a * s4.x;
        accss[1] += a * s4.y;
        accss[2] += a * s4.z;
        accss[3] += a * s4.w;
        const float4* xv = (const float4*)(x + node * F_DIMC + f0);
#pragma unroll
        for (int j = 0; j < 4; ++j) {
            float4 v = xv[j];
            accsx[4 * j + 0] += a * v.x;
            accsx[4 * j + 1] += a * v.y;
            accsx[4 * j + 2] += a * v.z;
            accsx[4 * j + 3] += a * v.w;
        }
    }
    __shared__ float lsx[SX_WAVES][K_DIMC * F_DIMC];  // 32 KB
    __shared__ float lss[SX_WAVES][256];              // 8 KB
#pragma unroll
    for (int j4 = 0; j4 < 4; ++j4) {
        float4* d = (float4*)&lsx[wid][k * F_DIMC + f0 + 4 * j4];
        *d = make_float4(accsx[4 * j4], accsx[4 * j4 + 1], accsx[4 * j4 + 2], accsx[4 * j4 + 3]);
    }
    {
        float4* d = (float4*)&lss[wid][k * K_DIMC + j0];
        *d = make_float4(accss[0], accss[1], accss[2], accss[3]);
    }
    __syncthreads();
    // SX: 1024 cells, 512 threads -> 2 cells each; cell c = k*64 + f matches out layout
    for (int c = threadIdx.x; c < K_DIMC * F_DIMC; c += 512) {
        float s = 0.f;
#pragma unroll
        for (int w = 0; w < SX_WAVES; ++w) s += lsx[w][c];
        atomicAdd(out + (size_t)g * (K_DIMC * F_DIMC) + c, s);
    }
    if (threadIdx.x < 256) {
        int c = threadIdx.x;
        float s = 0.f;
#pragma unroll
        for (int w = 0; w < SX_WAVES; ++w) s += lss[w][c];
        atomicAdd(ssbuf + g * 256 + c, s);
    }
}

__global__ void k_fin(const float* __restrict__ dense_raw, const float* __restrict__ ssbuf,
                      const float* __restrict__ den, float* __restrict__ out) {
    int g = threadIdx.x;  // 64 threads, one per graph
    const float* A = dense_raw + g * 256;
    float dv[K_DIMC];
#pragma unroll
    for (int k = 0; k < K_DIMC; ++k) {
        float s = 0.f;
#pragma unroll
        for (int j = 0; j < K_DIMC; ++j) s += A[k * K_DIMC + j];
        dv[k] = sqrtf(s) + 1e-15f;
    }
    float* Ao = out + NGRAPH * K_DIMC * F_DIMC + g * 256;
    float tr = 0.f;
#pragma unroll
    for (int k = 0; k < K_DIMC; ++k) {
#pragma unroll
        for (int j = 0; j < K_DIMC; ++j) {
            float v = A[k * K_DIMC + j] / (dv[k] * dv[j]);
            Ao[k * K_DIMC + j] = v;
            if (k == j) tr += v;
        }
    }
    float mterm = -(tr / den[g]);

    const float* SS = ssbuf + g * 256;
    float nrm2 = 0.f;
    for (int c = 0; c < 256; ++c) nrm2 += SS[c] * SS[c];
    float invn = 1.f / sqrtf(nrm2);
    float osum = 0.f;
#pragma unroll
    for (int k = 0; k < K_DIMC; ++k) {
#pragma unroll
        for (int j = 0; j < K_DIMC; ++j) {
            float v = SS[k * K_DIMC + j] * invn - ((k == j) ? 0.25f : 0.f);
            osum += v * v;
        }
    }
    float og = sqrtf(osum);

    float a = mterm, b2 = og;
#pragma unroll
    for (int off = 32; off > 0; off >>= 1) {
        a += __shfl_down(a, off);
        b2 += __shfl_down(b2, off);
    }
    if (g == 0) {
        out[NGRAPH * K_DIMC * F_DIMC + NGRAPH * K_DIMC * K_DIMC + 0] = a / (float)NGRAPH;
        out[NGRAPH * K_DIMC * F_DIMC + NGRAPH * K_DIMC * K_DIMC + 1] = b2 / (float)NGRAPH;
    }
}

extern "C" void kernel_launch(void* const* d_in, const int* in_sizes, int n_in,
                              void* d_out, int out_size, void* d_ws, size_t ws_size,
                              hipStream_t stream) {
    const float* node_attr = (const float*)d_in[0];
    const float* W = (const float*)d_in[1];
    const float* bias = (const float*)d_in[2];
    const int* edge_index = (const int*)d_in[3];
    int N = in_sizes[0] / F_DIMC;
    int E = in_sizes[3] / 2;
    int perG = N / NGRAPH;
    const int* row = edge_index;
    const int* col = edge_index + E;
    float* out = (float*)d_out;
    char* ws = (char*)d_ws;

    int* hist = (int*)(ws + 0);
    int* cursor = (int*)(ws + 256);
    float* den = (float*)(ws + 512);
    float* dense_raw = (float*)(ws + 1024);
    float* ssbuf = (float*)(ws + 66560);
    int* offsets = (int*)(ws + 132096);
    float* sel = (float*)(ws + 132352);
    float* q = (float*)(ws + 6685952);
    uint2* sorted = (uint2*)(ws + 7095552);

    // zero hist/cursor/den/dense_raw/ssbuf; plus SX region of out (atomic-accumulated)
    hipMemsetAsync(ws, 0, 132096, stream);
    hipMemsetAsync(out, 0, (size_t)NGRAPH * K_DIMC * F_DIMC * sizeof(float), stream);

    k_selection<<<(N + 255) / 256, 256, 0, stream>>>(node_attr, W, bias, sel, q, N);
    k_hist<<<(E / 4 + 511) / 512, 512, 0, stream>>>(row, q, hist, den, E / 4, perG);
    k_scan<<<1, 64, 0, stream>>>(hist, offsets, cursor);
    k_scatter<<<(E + 511) / 512, 512, 0, stream>>>(row, col, cursor, sorted, E, perG);
    k_adj<<<dim3(ADJ_SPLIT, NGRAPH), 256, 0, stream>>>(sorted, offsets, hist, sel, dense_raw);
    k_sx<<<dim3(SX_SPLIT, NGRAPH), 512, 0, stream>>>(sel, node_attr, ssbuf, out, perG);
    k_fin<<<1, 64, 0, stream>>>(dense_raw, ssbuf, den, out);
}

// Round 5
// 208.366 us; speedup vs baseline: 2.0609x; 1.0116x over previous
//
#include <hip/hip_runtime.h>

#define F_DIMC 64
#define K_DIMC 16
#define NGRAPH 64
#define SX_WAVES 8
#define SX_SPLIT 8
#define ADJ_SPLIT 32
#define NXCD 8

// ---------------- workspace layout (bytes) ----------------
// zeroed each call: [0, 132096)
//   [0,256)         hist (int[64])
//   [256,512)       cursor (int[64])
//   [512,768)       den (float[64])
//   [768,1024)      pad
//   [1024,66560)    dense_raw (float[64*256])
//   [66560,132096)  ssbuf (float[64*256])
// not zeroed:
//   [132096,132352)    offsets (int[64])
//   [132352,6685952)   sel (float[N*16])
//   [6685952,7095552)  q (float[N])
//   [7095552,13649152) sorted (uint2[E])

__global__ void k_selection(const float* __restrict__ node_attr,
                            const float* __restrict__ W,
                            const float* __restrict__ bias,
                            float* __restrict__ sel,
                            float* __restrict__ q,
                            int N) {
    __shared__ float sW[K_DIMC][F_DIMC];
    __shared__ float sb[K_DIMC];
    int t = threadIdx.x;
    for (int idx = t; idx < F_DIMC * K_DIMC; idx += blockDim.x) {
        int f = idx / K_DIMC, k = idx % K_DIMC;
        sW[k][f] = W[idx];
    }
    if (t < K_DIMC) sb[t] = bias[t];
    __syncthreads();
    int n = blockIdx.x * blockDim.x + t;
    if (n >= N) return;

    const float4* xr = (const float4*)(node_attr + (size_t)n * F_DIMC);
    float4 x[F_DIMC / 4];
#pragma unroll
    for (int f4 = 0; f4 < F_DIMC / 4; ++f4) x[f4] = xr[f4];

    float logits[K_DIMC];
#pragma unroll
    for (int k = 0; k < K_DIMC; ++k) {
        const float4* wk = (const float4*)&sW[k][0];
        float acc = sb[k];
#pragma unroll
        for (int f4 = 0; f4 < F_DIMC / 4; ++f4) {
            float4 w = wk[f4];
            acc += x[f4].x * w.x + x[f4].y * w.y + x[f4].z * w.z + x[f4].w * w.w;
        }
        logits[k] = acc;
    }
    float m = logits[0];
#pragma unroll
    for (int k = 1; k < K_DIMC; ++k) m = fmaxf(m, logits[k]);
    float sum = 0.f;
#pragma unroll
    for (int k = 0; k < K_DIMC; ++k) {
        float e = __expf(logits[k] - m);
        logits[k] = e;
        sum += e;
    }
    float inv = 1.f / sum;
    float qq = 0.f;
    float4* sd = (float4*)(sel + (size_t)n * K_DIMC);
#pragma unroll
    for (int k4 = 0; k4 < K_DIMC / 4; ++k4) {
        float4 v;
        v.x = logits[4 * k4 + 0] * inv;
        v.y = logits[4 * k4 + 1] * inv;
        v.z = logits[4 * k4 + 2] * inv;
        v.w = logits[4 * k4 + 3] * inv;
        qq += v.x * v.x + v.y * v.y + v.z * v.z + v.w * v.w;
        sd[k4] = v;
    }
    q[n] = qq;
}

// histogram of edges per graph + mincut_den[g] = sum_e q[row_e] (deg telescopes out).
// 4 edges per thread via int4 loads; LDS accumulation; 64+64 global atomics per block.
__global__ __launch_bounds__(512) void k_hist(const int* __restrict__ row,
                                              const float* __restrict__ q,
                                              int* __restrict__ hist,
                                              float* __restrict__ den,
                                              int E4, int perG) {
    __shared__ int lh[NGRAPH];
    __shared__ float lden[NGRAPH];
    if (threadIdx.x < NGRAPH) {
        lh[threadIdx.x] = 0;
        lden[threadIdx.x] = 0.f;
    }
    __syncthreads();
    int e4 = blockIdx.x * blockDim.x + threadIdx.x;
    if (e4 < E4) {
        int4 r4 = ((const int4*)row)[e4];
        int r[4] = {r4.x, r4.y, r4.z, r4.w};
#pragma unroll
        for (int j = 0; j < 4; ++j) {
            int g = r[j] / perG;
            atomicAdd(&lh[g], 1);
            atomicAdd(&lden[g], q[r[j]]);
        }
    }
    __syncthreads();
    if (threadIdx.x < NGRAPH) {
        int c = lh[threadIdx.x];
        if (c) {
            atomicAdd(&hist[threadIdx.x], c);
            atomicAdd(&den[threadIdx.x], lden[threadIdx.x]);
        }
    }
}

__global__ void k_scan(const int* __restrict__ hist, int* __restrict__ offsets,
                       int* __restrict__ cursor) {
    int t = threadIdx.x;  // 64 threads = 1 wave
    int v = hist[t];
    int sum = v;
#pragma unroll
    for (int d = 1; d < 64; d <<= 1) {
        int o = __shfl_up(sum, d);
        if (t >= d) sum += o;
    }
    int excl = sum - v;
    offsets[t] = excl;
    cursor[t] = excl;
}

__global__ void k_scatter(const int* __restrict__ row, const int* __restrict__ col,
                          int* __restrict__ cursor, uint2* __restrict__ sorted,
                          int E, int perG) {
    __shared__ int lcnt[NGRAPH];
    __shared__ int lbase[NGRAPH];
    if (threadIdx.x < NGRAPH) lcnt[threadIdx.x] = 0;
    __syncthreads();
    int e = blockIdx.x * blockDim.x + threadIdx.x;
    int r = 0, c = 0, g = 0, lpos = 0;
    bool valid = e < E;
    if (valid) {
        r = row[e];
        c = col[e];
        g = r / perG;
        lpos = atomicAdd(&lcnt[g], 1);
    }
    __syncthreads();
    if (threadIdx.x < NGRAPH) {
        int cnt = lcnt[threadIdx.x];
        lbase[threadIdx.x] = cnt ? atomicAdd(&cursor[threadIdx.x], cnt) : 0;
    }
    __syncthreads();
    if (valid) {
        sorted[(size_t)lbase[g] + lpos] = make_uint2((unsigned)r, (unsigned)c);
    }
}

// Flat 2048-block grid, XCD-swizzled so all 32 blocks of a graph land on ONE XCD
// (8 graphs per XCD; each graph's 100KB sel slice stays L2-resident).
// lane l -> (i=l>>2, j=(l&3)*4..+3); per-block LDS reduce across 4 waves,
// then ONE atomicAdd per cell per block.
__global__ __launch_bounds__(256) void k_adj(const uint2* __restrict__ sorted,
                                             const int* __restrict__ offsets,
                                             const int* __restrict__ hist,
                                             const float* __restrict__ sel,
                                             float* __restrict__ dense_raw) {
    int b = blockIdx.x;               // 0..2047, dispatched round-robin to XCDs
    int xcd = b & (NXCD - 1);
    int idx = b >> 3;                 // 0..255
    int g = xcd * (NGRAPH / NXCD) + (idx >> 5);
    int split = idx & (ADJ_SPLIT - 1);

    int start = offsets[g];
    int cnt = hist[g];
    int wavesPerGraph = ADJ_SPLIT * 4;
    int wid = threadIdx.x >> 6;
    int wseq = split * 4 + wid;
    int lane = threadIdx.x & 63;
    int i = lane >> 2;
    int j0 = (lane & 3) * 4;
    float ax = 0.f, ay = 0.f, az = 0.f, aw = 0.f;
#pragma unroll 8
    for (int e = wseq; e < cnt; e += wavesPerGraph) {
        uint2 pr = sorted[(size_t)start + e];
        float a = sel[(size_t)pr.x * K_DIMC + i];
        float4 bv = *(const float4*)(sel + (size_t)pr.y * K_DIMC + j0);
        ax += a * bv.x;
        ay += a * bv.y;
        az += a * bv.z;
        aw += a * bv.w;
    }
    __shared__ float lacc[4][256];
    int cell = i * K_DIMC + j0;
    float4* lw = (float4*)&lacc[wid][cell];
    *lw = make_float4(ax, ay, az, aw);
    __syncthreads();
    int c = threadIdx.x;  // 256 threads, one cell each
    float s = lacc[0][c] + lacc[1][c] + lacc[2][c] + lacc[3][c];
    atomicAdd(dense_raw + g * 256 + c, s);
}

// grid (SX_SPLIT, NGRAPH), 8 waves/block; lane l -> k=l>>2, sub=l&3;
// owns SX cells [k][sub*16..+15], SS cells [k][sub*4..+3].
// LDS reduce within block, then one atomicAdd per cell per block (8 contenders).
__global__ __launch_bounds__(512) void k_sx(const float* __restrict__ sel,
                                            const float* __restrict__ x,
                                            float* __restrict__ ssbuf,
                                            float* __restrict__ out, int perG) {
    int g = blockIdx.y;
    int wid = threadIdx.x >> 6;
    int wslot = blockIdx.x * SX_WAVES + wid;     // 0..63
    int lane = threadIdx.x & 63;
    int k = lane >> 2;
    int sub = lane & 3;
    int f0 = sub * 16;
    int j0 = sub * 4;
    float accss[4] = {0.f, 0.f, 0.f, 0.f};
    float accsx[16];
#pragma unroll
    for (int j = 0; j < 16; ++j) accsx[j] = 0.f;
    size_t base = (size_t)g * perG;
    int stride = SX_SPLIT * SX_WAVES;            // 64
#pragma unroll 2
    for (int nn = wslot; nn < perG; nn += stride) {
        size_t node = base + nn;
        float a = sel[node * K_DIMC + k];
        float4 s4 = *(const float4*)(sel + node * K_DIMC + j0);
        accss[0] += a * s4.x;
        accss[1] += a * s4.y;
        accss[2] += a * s4.z;
        accss[3] += a * s4.w;
        const float4* xv = (const float4*)(x + node * F_DIMC + f0);
#pragma unroll
        for (int j = 0; j < 4; ++j) {
            float4 v = xv[j];
            accsx[4 * j + 0] += a * v.x;
            accsx[4 * j + 1] += a * v.y;
            accsx[4 * j + 2] += a * v.z;
            accsx[4 * j + 3] += a * v.w;
        }
    }
    __shared__ float lsx[SX_WAVES][K_DIMC * F_DIMC];  // 32 KB
    __shared__ float lss[SX_WAVES][256];              // 8 KB
#pragma unroll
    for (int j4 = 0; j4 < 4; ++j4) {
        float4* d = (float4*)&lsx[wid][k * F_DIMC + f0 + 4 * j4];
        *d = make_float4(accsx[4 * j4], accsx[4 * j4 + 1], accsx[4 * j4 + 2], accsx[4 * j4 + 3]);
    }
    {
        float4* d = (float4*)&lss[wid][k * K_DIMC + j0];
        *d = make_float4(accss[0], accss[1], accss[2], accss[3]);
    }
    __syncthreads();
    // SX: 1024 cells, 512 threads -> 2 cells each; cell c = k*64 + f matches out layout
    for (int c = threadIdx.x; c < K_DIMC * F_DIMC; c += 512) {
        float s = 0.f;
#pragma unroll
        for (int w = 0; w < SX_WAVES; ++w) s += lsx[w][c];
        atomicAdd(out + (size_t)g * (K_DIMC * F_DIMC) + c, s);
    }
    if (threadIdx.x < 256) {
        int c = threadIdx.x;
        float s = 0.f;
#pragma unroll
        for (int w = 0; w < SX_WAVES; ++w) s += lss[w][c];
        atomicAdd(ssbuf + g * 256 + c, s);
    }
}

__global__ void k_fin(const float* __restrict__ dense_raw, const float* __restrict__ ssbuf,
                      const float* __restrict__ den, float* __restrict__ out) {
    int g = threadIdx.x;  // 64 threads, one per graph
    const float* A = dense_raw + g * 256;
    float dv[K_DIMC];
#pragma unroll
    for (int k = 0; k < K_DIMC; ++k) {
        float s = 0.f;
#pragma unroll
        for (int j = 0; j < K_DIMC; ++j) s += A[k * K_DIMC + j];
        dv[k] = sqrtf(s) + 1e-15f;
    }
    float* Ao = out + NGRAPH * K_DIMC * F_DIMC + g * 256;
    float tr = 0.f;
#pragma unroll
    for (int k = 0; k < K_DIMC; ++k) {
#pragma unroll
        for (int j = 0; j < K_DIMC; ++j) {
            float v = A[k * K_DIMC + j] / (dv[k] * dv[j]);
            Ao[k * K_DIMC + j] = v;
            if (k == j) tr += v;
        }
    }
    float mterm = -(tr / den[g]);

    const float* SS = ssbuf + g * 256;
    float nrm2 = 0.f;
    for (int c = 0; c < 256; ++c) nrm2 += SS[c] * SS[c];
    float invn = 1.f / sqrtf(nrm2);
    float osum = 0.f;
#pragma unroll
    for (int k = 0; k < K_DIMC; ++k) {
#pragma unroll
        for (int j = 0; j < K_DIMC; ++j) {
            float v = SS[k * K_DIMC + j] * invn - ((k == j) ? 0.25f : 0.f);
            osum += v * v;
        }
    }
    float og = sqrtf(osum);

    float a = mterm, b2 = og;
#pragma unroll
    for (int off = 32; off > 0; off >>= 1) {
        a += __shfl_down(a, off);
        b2 += __shfl_down(b2, off);
    }
    if (g == 0) {
        out[NGRAPH * K_DIMC * F_DIMC + NGRAPH * K_DIMC * K_DIMC + 0] = a / (float)NGRAPH;
        out[NGRAPH * K_DIMC * F_DIMC + NGRAPH * K_DIMC * K_DIMC + 1] = b2 / (float)NGRAPH;
    }
}

extern "C" void kernel_launch(void* const* d_in, const int* in_sizes, int n_in,
                              void* d_out, int out_size, void* d_ws, size_t ws_size,
                              hipStream_t stream) {
    const float* node_attr = (const float*)d_in[0];
    const float* W = (const float*)d_in[1];
    const float* bias = (const float*)d_in[2];
    const int* edge_index = (const int*)d_in[3];
    int N = in_sizes[0] / F_DIMC;
    int E = in_sizes[3] / 2;
    int perG = N / NGRAPH;
    const int* row = edge_index;
    const int* col = edge_index + E;
    float* out = (float*)d_out;
    char* ws = (char*)d_ws;

    int* hist = (int*)(ws + 0);
    int* cursor = (int*)(ws + 256);
    float* den = (float*)(ws + 512);
    float* dense_raw = (float*)(ws + 1024);
    float* ssbuf = (float*)(ws + 66560);
    int* offsets = (int*)(ws + 132096);
    float* sel = (float*)(ws + 132352);
    float* q = (float*)(ws + 6685952);
    uint2* sorted = (uint2*)(ws + 7095552);

    // zero hist/cursor/den/dense_raw/ssbuf; plus SX region of out (atomic-accumulated)
    hipMemsetAsync(ws, 0, 132096, stream);
    hipMemsetAsync(out, 0, (size_t)NGRAPH * K_DIMC * F_DIMC * sizeof(float), stream);

    k_selection<<<(N + 255) / 256, 256, 0, stream>>>(node_attr, W, bias, sel, q, N);
    k_hist<<<(E / 4 + 511) / 512, 512, 0, stream>>>(row, q, hist, den, E / 4, perG);
    k_scan<<<1, 64, 0, stream>>>(hist, offsets, cursor);
    k_scatter<<<(E + 511) / 512, 512, 0, stream>>>(row, col, cursor, sorted, E, perG);
    k_adj<<<ADJ_SPLIT * NGRAPH, 256, 0, stream>>>(sorted, offsets, hist, sel, dense_raw);
    k_sx<<<dim3(SX_SPLIT, NGRAPH), 512, 0, stream>>>(sel, node_attr, ssbuf, out, perG);
    k_fin<<<1, 64, 0, stream>>>(dense_raw, ssbuf, den, out);
}

// Round 6
// 181.080 us; speedup vs baseline: 2.3714x; 1.1507x over previous
//
#include <hip/hip_runtime.h>

#define F_DIMC 64
#define K_DIMC 16
#define NGRAPH 64
#define SX_WAVES 8
#define SX_SPLIT 8
#define ADJ_SPLIT 32
#define NXCD 8

// ---------------- workspace layout (bytes) ----------------
// zeroed each call: [0, 132096)
//   [0,256)         hist (int[64])
//   [256,512)       cursor (int[64])
//   [512,768)       den (float[64])
//   [768,1024)      pad
//   [1024,66560)    dense_raw (float[64*256])
//   [66560,132096)  ssbuf (float[64*256])
// not zeroed:
//   [132096,132352)    offsets (int[64])
//   [132352,6685952)   sel (float[N*16])
//   [6685952,7095552)  q (float[N])
//   [7095552,13649152) sorted (uint2[E])

__global__ void k_selection(const float* __restrict__ node_attr,
                            const float* __restrict__ W,
                            const float* __restrict__ bias,
                            float* __restrict__ sel,
                            float* __restrict__ q,
                            int N) {
    __shared__ float sW[K_DIMC][F_DIMC];
    __shared__ float sb[K_DIMC];
    int t = threadIdx.x;
    for (int idx = t; idx < F_DIMC * K_DIMC; idx += blockDim.x) {
        int f = idx / K_DIMC, k = idx % K_DIMC;
        sW[k][f] = W[idx];
    }
    if (t < K_DIMC) sb[t] = bias[t];
    __syncthreads();
    int n = blockIdx.x * blockDim.x + t;
    if (n >= N) return;

    const float4* xr = (const float4*)(node_attr + (size_t)n * F_DIMC);
    float4 x[F_DIMC / 4];
#pragma unroll
    for (int f4 = 0; f4 < F_DIMC / 4; ++f4) x[f4] = xr[f4];

    float logits[K_DIMC];
#pragma unroll
    for (int k = 0; k < K_DIMC; ++k) {
        const float4* wk = (const float4*)&sW[k][0];
        float acc = sb[k];
#pragma unroll
        for (int f4 = 0; f4 < F_DIMC / 4; ++f4) {
            float4 w = wk[f4];
            acc += x[f4].x * w.x + x[f4].y * w.y + x[f4].z * w.z + x[f4].w * w.w;
        }
        logits[k] = acc;
    }
    float m = logits[0];
#pragma unroll
    for (int k = 1; k < K_DIMC; ++k) m = fmaxf(m, logits[k]);
    float sum = 0.f;
#pragma unroll
    for (int k = 0; k < K_DIMC; ++k) {
        float e = __expf(logits[k] - m);
        logits[k] = e;
        sum += e;
    }
    float inv = 1.f / sum;
    float qq = 0.f;
    float4* sd = (float4*)(sel + (size_t)n * K_DIMC);
#pragma unroll
    for (int k4 = 0; k4 < K_DIMC / 4; ++k4) {
        float4 v;
        v.x = logits[4 * k4 + 0] * inv;
        v.y = logits[4 * k4 + 1] * inv;
        v.z = logits[4 * k4 + 2] * inv;
        v.w = logits[4 * k4 + 3] * inv;
        qq += v.x * v.x + v.y * v.y + v.z * v.z + v.w * v.w;
        sd[k4] = v;
    }
    q[n] = qq;
}

// histogram of edges per graph + mincut_den[g] = sum_e q[row_e] (deg telescopes out).
// 4 edges per thread via int4 loads; LDS accumulation; 64+64 global atomics per block.
__global__ __launch_bounds__(512) void k_hist(const int* __restrict__ row,
                                              const float* __restrict__ q,
                                              int* __restrict__ hist,
                                              float* __restrict__ den,
                                              int E4, int perG) {
    __shared__ int lh[NGRAPH];
    __shared__ float lden[NGRAPH];
    if (threadIdx.x < NGRAPH) {
        lh[threadIdx.x] = 0;
        lden[threadIdx.x] = 0.f;
    }
    __syncthreads();
    int e4 = blockIdx.x * blockDim.x + threadIdx.x;
    if (e4 < E4) {
        int4 r4 = ((const int4*)row)[e4];
        int r[4] = {r4.x, r4.y, r4.z, r4.w};
#pragma unroll
        for (int j = 0; j < 4; ++j) {
            int g = r[j] / perG;
            atomicAdd(&lh[g], 1);
            atomicAdd(&lden[g], q[r[j]]);
        }
    }
    __syncthreads();
    if (threadIdx.x < NGRAPH) {
        int c = lh[threadIdx.x];
        if (c) {
            atomicAdd(&hist[threadIdx.x], c);
            atomicAdd(&den[threadIdx.x], lden[threadIdx.x]);
        }
    }
}

__global__ void k_scan(const int* __restrict__ hist, int* __restrict__ offsets,
                       int* __restrict__ cursor) {
    int t = threadIdx.x;  // 64 threads = 1 wave
    int v = hist[t];
    int sum = v;
#pragma unroll
    for (int d = 1; d < 64; d <<= 1) {
        int o = __shfl_up(sum, d);
        if (t >= d) sum += o;
    }
    int excl = sum - v;
    offsets[t] = excl;
    cursor[t] = excl;
}

__global__ void k_scatter(const int* __restrict__ row, const int* __restrict__ col,
                          int* __restrict__ cursor, uint2* __restrict__ sorted,
                          int E, int perG) {
    __shared__ int lcnt[NGRAPH];
    __shared__ int lbase[NGRAPH];
    if (threadIdx.x < NGRAPH) lcnt[threadIdx.x] = 0;
    __syncthreads();
    int e = blockIdx.x * blockDim.x + threadIdx.x;
    int r = 0, c = 0, g = 0, lpos = 0;
    bool valid = e < E;
    if (valid) {
        r = row[e];
        c = col[e];
        g = r / perG;
        lpos = atomicAdd(&lcnt[g], 1);
    }
    __syncthreads();
    if (threadIdx.x < NGRAPH) {
        int cnt = lcnt[threadIdx.x];
        lbase[threadIdx.x] = cnt ? atomicAdd(&cursor[threadIdx.x], cnt) : 0;
    }
    __syncthreads();
    if (valid) {
        sorted[(size_t)lbase[g] + lpos] = make_uint2((unsigned)r, (unsigned)c);
    }
}

// Flat 2048-block grid, XCD-swizzled so all 32 blocks of a graph land on ONE XCD.
// Each wave owns a CONTIGUOUS chunk of its graph's edges; per 64-edge batch:
// one coalesced uint2 load (edge per lane), then a uniform inner loop broadcasting
// (r,c) via v_readlane (SALU) -> sel gathers use SGPR base + fixed lane offset.
// All sel loads of a batch are independent -> deep MLP over ~200cy L2 latency.
__global__ __launch_bounds__(256) void k_adj(const uint2* __restrict__ sorted,
                                             const int* __restrict__ offsets,
                                             const int* __restrict__ hist,
                                             const float* __restrict__ sel,
                                             float* __restrict__ dense_raw) {
    int b = blockIdx.x;               // 0..2047, dispatched round-robin to XCDs
    int xcd = b & (NXCD - 1);
    int idx = b >> 3;                 // 0..255
    int g = xcd * (NGRAPH / NXCD) + (idx >> 5);
    int split = idx & (ADJ_SPLIT - 1);

    int start = offsets[g];
    int cnt = hist[g];
    int wavesPerGraph = ADJ_SPLIT * 4;        // 128
    int wid = threadIdx.x >> 6;
    int wseq = split * 4 + wid;
    int lane = threadIdx.x & 63;
    int i = lane >> 2;
    int j0 = (lane & 3) * 4;

    int chunk = (cnt + wavesPerGraph - 1) / wavesPerGraph;
    int myStart = start + wseq * chunk;
    int myEnd = start + cnt;
    if (myStart + chunk < myEnd) myEnd = myStart + chunk;

    float ax = 0.f, ay = 0.f, az = 0.f, aw = 0.f;
    for (int r0 = myStart; r0 < myEnd; r0 += 64) {
        int nb = myEnd - r0;
        if (nb > 64) nb = 64;
        int li = r0 + (lane < nb ? lane : nb - 1);
        uint2 pr = sorted[li];
        int rx = (int)pr.x * K_DIMC;
        int cx = (int)pr.y * K_DIMC;
#pragma unroll 8
        for (int ee = 0; ee < nb; ++ee) {
            int rb = __builtin_amdgcn_readlane(rx, ee);
            int cb = __builtin_amdgcn_readlane(cx, ee);
            float a = sel[rb + i];
            float4 bv = *(const float4*)(sel + cb + j0);
            ax = fmaf(a, bv.x, ax);
            ay = fmaf(a, bv.y, ay);
            az = fmaf(a, bv.z, az);
            aw = fmaf(a, bv.w, aw);
        }
    }
    __shared__ float lacc[4][256];
    int cell = i * K_DIMC + j0;
    float4* lw = (float4*)&lacc[wid][cell];
    *lw = make_float4(ax, ay, az, aw);
    __syncthreads();
    int c = threadIdx.x;  // 256 threads, one cell each
    float s = lacc[0][c] + lacc[1][c] + lacc[2][c] + lacc[3][c];
    atomicAdd(dense_raw + g * 256 + c, s);
}

// grid (SX_SPLIT, NGRAPH), 8 waves/block; lane l -> k=l>>2, sub=l&3;
// owns SX cells [k][sub*16..+15], SS cells [k][sub*4..+3].
// LDS reduce within block, then one atomicAdd per cell per block (8 contenders).
__global__ __launch_bounds__(512) void k_sx(const float* __restrict__ sel,
                                            const float* __restrict__ x,
                                            float* __restrict__ ssbuf,
                                            float* __restrict__ out, int perG) {
    int g = blockIdx.y;
    int wid = threadIdx.x >> 6;
    int wslot = blockIdx.x * SX_WAVES + wid;     // 0..63
    int lane = threadIdx.x & 63;
    int k = lane >> 2;
    int sub = lane & 3;
    int f0 = sub * 16;
    int j0 = sub * 4;
    float accss[4] = {0.f, 0.f, 0.f, 0.f};
    float accsx[16];
#pragma unroll
    for (int j = 0; j < 16; ++j) accsx[j] = 0.f;
    size_t base = (size_t)g * perG;
    int stride = SX_SPLIT * SX_WAVES;            // 64
#pragma unroll 2
    for (int nn = wslot; nn < perG; nn += stride) {
        size_t node = base + nn;
        float a = sel[node * K_DIMC + k];
        float4 s4 = *(const float4*)(sel + node * K_DIMC + j0);
        accss[0] += a * s4.x;
        accss[1] += a * s4.y;
        accss[2] += a * s4.z;
        accss[3] += a * s4.w;
        const float4* xv = (const float4*)(x + node * F_DIMC + f0);
#pragma unroll
        for (int j = 0; j < 4; ++j) {
            float4 v = xv[j];
            accsx[4 * j + 0] += a * v.x;
            accsx[4 * j + 1] += a * v.y;
            accsx[4 * j + 2] += a * v.z;
            accsx[4 * j + 3] += a * v.w;
        }
    }
    __shared__ float lsx[SX_WAVES][K_DIMC * F_DIMC];  // 32 KB
    __shared__ float lss[SX_WAVES][256];              // 8 KB
#pragma unroll
    for (int j4 = 0; j4 < 4; ++j4) {
        float4* d = (float4*)&lsx[wid][k * F_DIMC + f0 + 4 * j4];
        *d = make_float4(accsx[4 * j4], accsx[4 * j4 + 1], accsx[4 * j4 + 2], accsx[4 * j4 + 3]);
    }
    {
        float4* d = (float4*)&lss[wid][k * K_DIMC + j0];
        *d = make_float4(accss[0], accss[1], accss[2], accss[3]);
    }
    __syncthreads();
    // SX: 1024 cells, 512 threads -> 2 cells each; cell c = k*64 + f matches out layout
    for (int c = threadIdx.x; c < K_DIMC * F_DIMC; c += 512) {
        float s = 0.f;
#pragma unroll
        for (int w = 0; w < SX_WAVES; ++w) s += lsx[w][c];
        atomicAdd(out + (size_t)g * (K_DIMC * F_DIMC) + c, s);
    }
    if (threadIdx.x < 256) {
        int c = threadIdx.x;
        float s = 0.f;
#pragma unroll
        for (int w = 0; w < SX_WAVES; ++w) s += lss[w][c];
        atomicAdd(ssbuf + g * 256 + c, s);
    }
}

__global__ void k_fin(const float* __restrict__ dense_raw, const float* __restrict__ ssbuf,
                      const float* __restrict__ den, float* __restrict__ out) {
    int g = threadIdx.x;  // 64 threads, one per graph
    const float* A = dense_raw + g * 256;
    float dv[K_DIMC];
#pragma unroll
    for (int k = 0; k < K_DIMC; ++k) {
        float s = 0.f;
#pragma unroll
        for (int j = 0; j < K_DIMC; ++j) s += A[k * K_DIMC + j];
        dv[k] = sqrtf(s) + 1e-15f;
    }
    float* Ao = out + NGRAPH * K_DIMC * F_DIMC + g * 256;
    float tr = 0.f;
#pragma unroll
    for (int k = 0; k < K_DIMC; ++k) {
#pragma unroll
        for (int j = 0; j < K_DIMC; ++j) {
            float v = A[k * K_DIMC + j] / (dv[k] * dv[j]);
            Ao[k * K_DIMC + j] = v;
            if (k == j) tr += v;
        }
    }
    float mterm = -(tr / den[g]);

    const float* SS = ssbuf + g * 256;
    float nrm2 = 0.f;
    for (int c = 0; c < 256; ++c) nrm2 += SS[c] * SS[c];
    float invn = 1.f / sqrtf(nrm2);
    float osum = 0.f;
#pragma unroll
    for (int k = 0; k < K_DIMC; ++k) {
#pragma unroll
        for (int j = 0; j < K_DIMC; ++j) {
            float v = SS[k * K_DIMC + j] * invn - ((k == j) ? 0.25f : 0.f);
            osum += v * v;
        }
    }
    float og = sqrtf(osum);

    float a = mterm, b2 = og;
#pragma unroll
    for (int off = 32; off > 0; off >>= 1) {
        a += __shfl_down(a, off);
        b2 += __shfl_down(b2, off);
    }
    if (g == 0) {
        out[NGRAPH * K_DIMC * F_DIMC + NGRAPH * K_DIMC * K_DIMC + 0] = a / (float)NGRAPH;
        out[NGRAPH * K_DIMC * F_DIMC + NGRAPH * K_DIMC * K_DIMC + 1] = b2 / (float)NGRAPH;
    }
}

extern "C" void kernel_launch(void* const* d_in, const int* in_sizes, int n_in,
                              void* d_out, int out_size, void* d_ws, size_t ws_size,
                              hipStream_t stream) {
    const float* node_attr = (const float*)d_in[0];
    const float* W = (const float*)d_in[1];
    const float* bias = (const float*)d_in[2];
    const int* edge_index = (const int*)d_in[3];
    int N = in_sizes[0] / F_DIMC;
    int E = in_sizes[3] / 2;
    int perG = N / NGRAPH;
    const int* row = edge_index;
    const int* col = edge_index + E;
    float* out = (float*)d_out;
    char* ws = (char*)d_ws;

    int* hist = (int*)(ws + 0);
    int* cursor = (int*)(ws + 256);
    float* den = (float*)(ws + 512);
    float* dense_raw = (float*)(ws + 1024);
    float* ssbuf = (float*)(ws + 66560);
    int* offsets = (int*)(ws + 132096);
    float* sel = (float*)(ws + 132352);
    float* q = (float*)(ws + 6685952);
    uint2* sorted = (uint2*)(ws + 7095552);

    // zero hist/cursor/den/dense_raw/ssbuf; plus SX region of out (atomic-accumulated)
    hipMemsetAsync(ws, 0, 132096, stream);
    hipMemsetAsync(out, 0, (size_t)NGRAPH * K_DIMC * F_DIMC * sizeof(float), stream);

    k_selection<<<(N + 255) / 256, 256, 0, stream>>>(node_attr, W, bias, sel, q, N);
    k_hist<<<(E / 4 + 511) / 512, 512, 0, stream>>>(row, q, hist, den, E / 4, perG);
    k_scan<<<1, 64, 0, stream>>>(hist, offsets, cursor);
    k_scatter<<<(E + 511) / 512, 512, 0, stream>>>(row, col, cursor, sorted, E, perG);
    k_adj<<<ADJ_SPLIT * NGRAPH, 256, 0, stream>>>(sorted, offsets, hist, sel, dense_raw);
    k_sx<<<dim3(SX_SPLIT, NGRAPH), 512, 0, stream>>>(sel, node_attr, ssbuf, out, perG);
    k_fin<<<1, 64, 0, stream>>>(dense_raw, ssbuf, den, out);
}

// Round 7
// 148.056 us; speedup vs baseline: 2.9004x; 1.2231x over previous
//
#include <hip/hip_runtime.h>

#define F_DIMC 64
#define K_DIMC 16
#define NGRAPH 64
#define SX_WAVES 8
#define SX_SPLIT 8
#define ADJ_SPLIT 32
#define NXCD 8
#define ADJ_OFF (NGRAPH * K_DIMC * F_DIMC)
#define LOSS_OFF (NGRAPH * K_DIMC * F_DIMC + NGRAPH * K_DIMC * K_DIMC)

// ---------------- workspace layout (bytes) ----------------
// zeroed each call: [0, 132096)
//   [0,256)         hist (int[64])
//   [256,512)       cursor (int[64])
//   [512,768)       den (float[64])
//   [768,1024)      pad
//   [1024,66560)    dense_raw (float[64*256])
//   [66560,132096)  ssbuf (float[64*256])
// not zeroed:
//   [132096,132352)    offsets (int[64])
//   [132352,6685952)   sel (float[N*16])
//   [6685952,7095552)  q (float[N])
//   [7095552,13649152) sorted (uint2[E])

__global__ void k_selection(const float* __restrict__ node_attr,
                            const float* __restrict__ W,
                            const float* __restrict__ bias,
                            float* __restrict__ sel,
                            float* __restrict__ q,
                            int N) {
    __shared__ float sW[K_DIMC][F_DIMC];
    __shared__ float sb[K_DIMC];
    int t = threadIdx.x;
    for (int idx = t; idx < F_DIMC * K_DIMC; idx += blockDim.x) {
        int f = idx / K_DIMC, k = idx % K_DIMC;
        sW[k][f] = W[idx];
    }
    if (t < K_DIMC) sb[t] = bias[t];
    __syncthreads();
    int n = blockIdx.x * blockDim.x + t;
    if (n >= N) return;

    const float4* xr = (const float4*)(node_attr + (size_t)n * F_DIMC);
    float4 x[F_DIMC / 4];
#pragma unroll
    for (int f4 = 0; f4 < F_DIMC / 4; ++f4) x[f4] = xr[f4];

    float logits[K_DIMC];
#pragma unroll
    for (int k = 0; k < K_DIMC; ++k) {
        const float4* wk = (const float4*)&sW[k][0];
        float acc = sb[k];
#pragma unroll
        for (int f4 = 0; f4 < F_DIMC / 4; ++f4) {
            float4 w = wk[f4];
            acc += x[f4].x * w.x + x[f4].y * w.y + x[f4].z * w.z + x[f4].w * w.w;
        }
        logits[k] = acc;
    }
    float m = logits[0];
#pragma unroll
    for (int k = 1; k < K_DIMC; ++k) m = fmaxf(m, logits[k]);
    float sum = 0.f;
#pragma unroll
    for (int k = 0; k < K_DIMC; ++k) {
        float e = __expf(logits[k] - m);
        logits[k] = e;
        sum += e;
    }
    float inv = 1.f / sum;
    float qq = 0.f;
    float4* sd = (float4*)(sel + (size_t)n * K_DIMC);
#pragma unroll
    for (int k4 = 0; k4 < K_DIMC / 4; ++k4) {
        float4 v;
        v.x = logits[4 * k4 + 0] * inv;
        v.y = logits[4 * k4 + 1] * inv;
        v.z = logits[4 * k4 + 2] * inv;
        v.w = logits[4 * k4 + 3] * inv;
        qq += v.x * v.x + v.y * v.y + v.z * v.z + v.w * v.w;
        sd[k4] = v;
    }
    q[n] = qq;
}

// histogram of edges per graph + mincut_den[g] = sum_e q[row_e] (deg telescopes out).
// 4 edges per thread via int4 loads; LDS accumulation; 64+64 global atomics per block.
__global__ __launch_bounds__(512) void k_hist(const int* __restrict__ row,
                                              const float* __restrict__ q,
                                              int* __restrict__ hist,
                                              float* __restrict__ den,
                                              int E4, int perG) {
    __shared__ int lh[NGRAPH];
    __shared__ float lden[NGRAPH];
    if (threadIdx.x < NGRAPH) {
        lh[threadIdx.x] = 0;
        lden[threadIdx.x] = 0.f;
    }
    __syncthreads();
    int e4 = blockIdx.x * blockDim.x + threadIdx.x;
    if (e4 < E4) {
        int4 r4 = ((const int4*)row)[e4];
        int r[4] = {r4.x, r4.y, r4.z, r4.w};
#pragma unroll
        for (int j = 0; j < 4; ++j) {
            int g = r[j] / perG;
            atomicAdd(&lh[g], 1);
            atomicAdd(&lden[g], q[r[j]]);
        }
    }
    __syncthreads();
    if (threadIdx.x < NGRAPH) {
        int c = lh[threadIdx.x];
        if (c) {
            atomicAdd(&hist[threadIdx.x], c);
            atomicAdd(&den[threadIdx.x], lden[threadIdx.x]);
        }
    }
}

__global__ void k_scan(const int* __restrict__ hist, int* __restrict__ offsets,
                       int* __restrict__ cursor) {
    int t = threadIdx.x;  // 64 threads = 1 wave
    int v = hist[t];
    int sum = v;
#pragma unroll
    for (int d = 1; d < 64; d <<= 1) {
        int o = __shfl_up(sum, d);
        if (t >= d) sum += o;
    }
    int excl = sum - v;
    offsets[t] = excl;
    cursor[t] = excl;
}

__global__ void k_scatter(const int* __restrict__ row, const int* __restrict__ col,
                          int* __restrict__ cursor, uint2* __restrict__ sorted,
                          int E, int perG) {
    __shared__ int lcnt[NGRAPH];
    __shared__ int lbase[NGRAPH];
    if (threadIdx.x < NGRAPH) lcnt[threadIdx.x] = 0;
    __syncthreads();
    int e = blockIdx.x * blockDim.x + threadIdx.x;
    int r = 0, c = 0, g = 0, lpos = 0;
    bool valid = e < E;
    if (valid) {
        r = row[e];
        c = col[e];
        g = r / perG;
        lpos = atomicAdd(&lcnt[g], 1);
    }
    __syncthreads();
    if (threadIdx.x < NGRAPH) {
        int cnt = lcnt[threadIdx.x];
        lbase[threadIdx.x] = cnt ? atomicAdd(&cursor[threadIdx.x], cnt) : 0;
    }
    __syncthreads();
    if (valid) {
        sorted[(size_t)lbase[g] + lpos] = make_uint2((unsigned)r, (unsigned)c);
    }
}

// Flat 2048-block grid, XCD-swizzled so all 32 blocks of a graph land on ONE XCD.
// Each wave owns a CONTIGUOUS chunk of its graph's edges; per 64-edge batch:
// one coalesced uint2 load (edge per lane), then a uniform inner loop broadcasting
// (r,c) via readlane -> sel gathers are independent within the batch (deep MLP).
__global__ __launch_bounds__(256) void k_adj(const uint2* __restrict__ sorted,
                                             const int* __restrict__ offsets,
                                             const int* __restrict__ hist,
                                             const float* __restrict__ sel,
                                             float* __restrict__ dense_raw) {
    int b = blockIdx.x;               // 0..2047, dispatched round-robin to XCDs
    int xcd = b & (NXCD - 1);
    int idx = b >> 3;                 // 0..255
    int g = xcd * (NGRAPH / NXCD) + (idx >> 5);
    int split = idx & (ADJ_SPLIT - 1);

    int start = offsets[g];
    int cnt = hist[g];
    int wavesPerGraph = ADJ_SPLIT * 4;        // 128
    int wid = threadIdx.x >> 6;
    int wseq = split * 4 + wid;
    int lane = threadIdx.x & 63;
    int i = lane >> 2;
    int j0 = (lane & 3) * 4;

    int chunk = (cnt + wavesPerGraph - 1) / wavesPerGraph;
    int myStart = start + wseq * chunk;
    int myEnd = start + cnt;
    if (myStart + chunk < myEnd) myEnd = myStart + chunk;

    float ax = 0.f, ay = 0.f, az = 0.f, aw = 0.f;
    for (int r0 = myStart; r0 < myEnd; r0 += 64) {
        int nb = myEnd - r0;
        if (nb > 64) nb = 64;
        int li = r0 + (lane < nb ? lane : nb - 1);
        uint2 pr = sorted[li];
        int rx = (int)pr.x * K_DIMC;
        int cx = (int)pr.y * K_DIMC;
#pragma unroll 8
        for (int ee = 0; ee < nb; ++ee) {
            int rb = __builtin_amdgcn_readlane(rx, ee);
            int cb = __builtin_amdgcn_readlane(cx, ee);
            float a = sel[rb + i];
            float4 bv = *(const float4*)(sel + cb + j0);
            ax = fmaf(a, bv.x, ax);
            ay = fmaf(a, bv.y, ay);
            az = fmaf(a, bv.z, az);
            aw = fmaf(a, bv.w, aw);
        }
    }
    __shared__ float lacc[4][256];
    int cell = i * K_DIMC + j0;
    float4* lw = (float4*)&lacc[wid][cell];
    *lw = make_float4(ax, ay, az, aw);
    __syncthreads();
    int c = threadIdx.x;  // 256 threads, one cell each
    float s = lacc[0][c] + lacc[1][c] + lacc[2][c] + lacc[3][c];
    atomicAdd(dense_raw + g * 256 + c, s);
}

// grid (SX_SPLIT, NGRAPH), 8 waves/block; lane l -> k=l>>2, sub=l&3;
// owns SX cells [k][sub*16..+15], SS cells [k][sub*4..+3].
// LDS reduce within block, then one atomicAdd per cell per block (8 contenders).
__global__ __launch_bounds__(512) void k_sx(const float* __restrict__ sel,
                                            const float* __restrict__ x,
                                            float* __restrict__ ssbuf,
                                            float* __restrict__ out, int perG) {
    int g = blockIdx.y;
    int wid = threadIdx.x >> 6;
    int wslot = blockIdx.x * SX_WAVES + wid;     // 0..63
    int lane = threadIdx.x & 63;
    int k = lane >> 2;
    int sub = lane & 3;
    int f0 = sub * 16;
    int j0 = sub * 4;
    float accss[4] = {0.f, 0.f, 0.f, 0.f};
    float accsx[16];
#pragma unroll
    for (int j = 0; j < 16; ++j) accsx[j] = 0.f;
    size_t base = (size_t)g * perG;
    int stride = SX_SPLIT * SX_WAVES;            // 64
#pragma unroll 2
    for (int nn = wslot; nn < perG; nn += stride) {
        size_t node = base + nn;
        float a = sel[node * K_DIMC + k];
        float4 s4 = *(const float4*)(sel + node * K_DIMC + j0);
        accss[0] += a * s4.x;
        accss[1] += a * s4.y;
        accss[2] += a * s4.z;
        accss[3] += a * s4.w;
        const float4* xv = (const float4*)(x + node * F_DIMC + f0);
#pragma unroll
        for (int j = 0; j < 4; ++j) {
            float4 v = xv[j];
            accsx[4 * j + 0] += a * v.x;
            accsx[4 * j + 1] += a * v.y;
            accsx[4 * j + 2] += a * v.z;
            accsx[4 * j + 3] += a * v.w;
        }
    }
    __shared__ float lsx[SX_WAVES][K_DIMC * F_DIMC];  // 32 KB
    __shared__ float lss[SX_WAVES][256];              // 8 KB
#pragma unroll
    for (int j4 = 0; j4 < 4; ++j4) {
        float4* d = (float4*)&lsx[wid][k * F_DIMC + f0 + 4 * j4];
        *d = make_float4(accsx[4 * j4], accsx[4 * j4 + 1], accsx[4 * j4 + 2], accsx[4 * j4 + 3]);
    }
    {
        float4* d = (float4*)&lss[wid][k * K_DIMC + j0];
        *d = make_float4(accss[0], accss[1], accss[2], accss[3]);
    }
    __syncthreads();
    // SX: 1024 cells, 512 threads -> 2 cells each; cell c = k*64 + f matches out layout
    for (int c = threadIdx.x; c < K_DIMC * F_DIMC; c += 512) {
        float s = 0.f;
#pragma unroll
        for (int w = 0; w < SX_WAVES; ++w) s += lsx[w][c];
        atomicAdd(out + (size_t)g * (K_DIMC * F_DIMC) + c, s);
    }
    if (threadIdx.x < 256) {
        int c = threadIdx.x;
        float s = 0.f;
#pragma unroll
        for (int w = 0; w < SX_WAVES; ++w) s += lss[w][c];
        atomicAdd(ssbuf + g * 256 + c, s);
    }
}

// one block per graph, 256 threads = one thread per 16x16 cell.
// Row sums via 16-lane shfl_xor groups; block reduces for trace/norm/ortho;
// per-graph loss terms atomically accumulated (pre-scaled by 1/NGRAPH).
__global__ __launch_bounds__(256) void k_fin(const float* __restrict__ dense_raw,
                                             const float* __restrict__ ssbuf,
                                             const float* __restrict__ den,
                                             float* __restrict__ out) {
    int g = blockIdx.x;
    int c = threadIdx.x;          // cell index
    int k = c >> 4, j = c & 15;
    int lane = threadIdx.x & 63;
    int wid = threadIdx.x >> 6;

    float a = dense_raw[g * 256 + c];
    // row sum over the 16-lane group (rows are 16-lane aligned)
    float s = a;
    s += __shfl_xor(s, 1);
    s += __shfl_xor(s, 2);
    s += __shfl_xor(s, 4);
    s += __shfl_xor(s, 8);
    __shared__ float dvrow[K_DIMC];
    if (j == 0) dvrow[k] = sqrtf(s) + 1e-15f;
    __syncthreads();
    float v = a / (dvrow[k] * dvrow[j]);
    out[ADJ_OFF + g * 256 + c] = v;

    // trace and ||SS||^2 block reductions (two wave-reduces share one sync)
    float ss = ssbuf[g * 256 + c];
    float t = (k == j) ? v : 0.f;
    float n2 = ss * ss;
#pragma unroll
    for (int off = 32; off > 0; off >>= 1) {
        t += __shfl_down(t, off);
        n2 += __shfl_down(n2, off);
    }
    __shared__ float redt[4], redn[4];
    if (lane == 0) { redt[wid] = t; redn[wid] = n2; }
    __syncthreads();
    float tr = redt[0] + redt[1] + redt[2] + redt[3];
    float nrm2 = redn[0] + redn[1] + redn[2] + redn[3];
    float invn = 1.f / sqrtf(nrm2);
    float d = ss * invn - ((k == j) ? 0.25f : 0.f);
    float o2 = d * d;
#pragma unroll
    for (int off = 32; off > 0; off >>= 1) o2 += __shfl_down(o2, off);
    __shared__ float redo[4];
    if (lane == 0) redo[wid] = o2;
    __syncthreads();
    if (threadIdx.x == 0) {
        float osum = redo[0] + redo[1] + redo[2] + redo[3];
        float og = sqrtf(osum);
        float mterm = -(tr / den[g]);
        atomicAdd(out + LOSS_OFF + 0, mterm * (1.f / NGRAPH));
        atomicAdd(out + LOSS_OFF + 1, og * (1.f / NGRAPH));
    }
}

extern "C" void kernel_launch(void* const* d_in, const int* in_sizes, int n_in,
                              void* d_out, int out_size, void* d_ws, size_t ws_size,
                              hipStream_t stream) {
    const float* node_attr = (const float*)d_in[0];
    const float* W = (const float*)d_in[1];
    const float* bias = (const float*)d_in[2];
    const int* edge_index = (const int*)d_in[3];
    int N = in_sizes[0] / F_DIMC;
    int E = in_sizes[3] / 2;
    int perG = N / NGRAPH;
    const int* row = edge_index;
    const int* col = edge_index + E;
    float* out = (float*)d_out;
    char* ws = (char*)d_ws;

    int* hist = (int*)(ws + 0);
    int* cursor = (int*)(ws + 256);
    float* den = (float*)(ws + 512);
    float* dense_raw = (float*)(ws + 1024);
    float* ssbuf = (float*)(ws + 66560);
    int* offsets = (int*)(ws + 132096);
    float* sel = (float*)(ws + 132352);
    float* q = (float*)(ws + 6685952);
    uint2* sorted = (uint2*)(ws + 7095552);

    // zero hist/cursor/den/dense_raw/ssbuf; SX region of out; the two loss scalars
    hipMemsetAsync(ws, 0, 132096, stream);
    hipMemsetAsync(out, 0, (size_t)NGRAPH * K_DIMC * F_DIMC * sizeof(float), stream);
    hipMemsetAsync(out + LOSS_OFF, 0, 2 * sizeof(float), stream);

    k_selection<<<(N + 255) / 256, 256, 0, stream>>>(node_attr, W, bias, sel, q, N);
    k_hist<<<(E / 4 + 511) / 512, 512, 0, stream>>>(row, q, hist, den, E / 4, perG);
    k_scan<<<1, 64, 0, stream>>>(hist, offsets, cursor);
    k_scatter<<<(E + 511) / 512, 512, 0, stream>>>(row, col, cursor, sorted, E, perG);
    k_adj<<<ADJ_SPLIT * NGRAPH, 256, 0, stream>>>(sorted, offsets, hist, sel, dense_raw);
    k_sx<<<dim3(SX_SPLIT, NGRAPH), 512, 0, stream>>>(sel, node_attr, ssbuf, out, perG);
    k_fin<<<NGRAPH, 256, 0, stream>>>(dense_raw, ssbuf, den, out);
}